// Round 8
// baseline (316.637 us; speedup 1.0000x reference)
//
#include <hip/hip_runtime.h>

// ROUND-8 MEASUREMENT PROBE: gemm1 is launched TWICE in the need_full path
// (identical args; second run rewrites identical bytes — correctness-safe).
// delta(total vs r7's 257.6) + polish(~4) = gemm1 duration. REMOVE NEXT ROUND.

typedef unsigned short u16;
typedef unsigned int u32;
typedef __attribute__((ext_vector_type(8))) short short8;
typedef __attribute__((ext_vector_type(4))) float f32x4;

__device__ __forceinline__ u16 f2b(float f) {  // RNE
  union { float f; unsigned u; } v; v.f = f;
  unsigned r = (v.u + 0x7FFFu + ((v.u >> 16) & 1u)) >> 16;
  return (u16)r;
}
__device__ __forceinline__ float b2f(u16 b) {
  union { unsigned u; float f; } v; v.u = ((unsigned)b) << 16;
  return v.f;
}
// Single-instruction packed f32->bf16 (RNE). T12 recipe: no builtin on gfx950.
__device__ __forceinline__ u32 cvtpk(float a, float b) {
  u32 r;
  asm("v_cvt_pk_bf16_f32 %0, %1, %2" : "=v"(r) : "v"(a), "v"(b));
  return r;
}
// Cross-lane row swaps (gfx950). Both operands are read-write.
__device__ __forceinline__ void p32swap(u32& a, u32& b) {
  asm("v_permlane32_swap_b32 %0, %1" : "+v"(a), "+v"(b));
}
__device__ __forceinline__ void p16swap(u32& a, u32& b) {
  asm("v_permlane16_swap_b32 %0, %1" : "+v"(a), "+v"(b));
}
__device__ __forceinline__ float ldf(const void* p, size_t i, int f32) {
  return f32 ? ((const float*)p)[i] : b2f(((const u16*)p)[i]);
}

// fp32 vs bf16 input detector (HW-verified; fp32 on this harness).
// Kept for the reduced-workspace fallback paths.
__global__ __launch_bounds__(256) void detect_dtype(const u16* __restrict__ x,
                                                    int* __restrict__ flag) {
  __shared__ int cnt;
  if (threadIdx.x == 0) cnt = 0;
  __syncthreads();
  int local = 0;
  for (int p = threadIdx.x; p < 512; p += 256) {
    int e = (x[2 * p] >> 7) & 0xFF;
    if (e >= 0xC0) local++;
  }
  atomicAdd(&cnt, local);
  __syncthreads();
  if (threadIdx.x == 0) flag[0] = (cnt >= 16) ? 1 : 0;
}

// Fused one-time fp32->bf16 convert of all 5 tensors (1 launch, self-detecting).
__global__ __launch_bounds__(256) void convert_all(
    const void* __restrict__ px, const void* __restrict__ pwq,
    const void* __restrict__ pbq, const void* __restrict__ pwo,
    const void* __restrict__ pbo, u16* __restrict__ xb,
    u16* __restrict__ wqkvb, u16* __restrict__ bqkvb, u16* __restrict__ wob,
    u16* __restrict__ bob) {
  __shared__ int sf;
  if (threadIdx.x == 0) sf = 0;
  __syncthreads();
  {
    const u16* xr = (const u16*)px;
    int local = 0;
    for (int p = threadIdx.x; p < 512; p += 256) {
      int e = (xr[2 * p] >> 7) & 0xFF;
      if (e >= 0xC0) local++;
    }
    atomicAdd(&sf, local);
  }
  __syncthreads();
  const int isf32 = (sf >= 16);

  int i = blockIdx.x * 256 + threadIdx.x;
  const void* in; u16* out; size_t g;
  if (i < 524288)       { in = px;  out = xb;    g = (size_t)i; }
  else if (i < 917504)  { in = pwq; out = wqkvb; g = (size_t)(i - 524288); }
  else if (i < 917888)  { in = pbq; out = bqkvb; g = (size_t)(i - 917504); }
  else if (i < 1048960) { in = pwo; out = wob;   g = (size_t)(i - 917888); }
  else                  { in = pbo; out = bob;   g = (size_t)(i - 1048960); }
  size_t base = g * 8;
  if (isf32) {
    const float* p = (const float*)in + base;
    float4 v0 = *(const float4*)p, v1 = *(const float4*)(p + 4);
    union { short8 v; u16 e[8]; } t;
    t.e[0]=f2b(v0.x); t.e[1]=f2b(v0.y); t.e[2]=f2b(v0.z); t.e[3]=f2b(v0.w);
    t.e[4]=f2b(v1.x); t.e[5]=f2b(v1.y); t.e[6]=f2b(v1.z); t.e[7]=f2b(v1.w);
    *(short8*)(out + base) = t.v;
  } else {
    *(short8*)(out + base) = *(const short8*)((const u16*)in + base);
  }
}

// qkv[n][3072] V-cols -> Vtg[h][64][4096]  (HW-verified)
__global__ __launch_bounds__(256) void transpose_v(const u16* __restrict__ qkv,
                                                   u16* __restrict__ Vt) {
  __shared__ u16 T[64 * 72];
  const int tid = threadIdx.x;
  const int h = blockIdx.y;
  const int s0 = blockIdx.x * 64;
  for (int r = 0; r < 2; ++r) {
    int cid = r * 256 + tid;
    int s = cid >> 3, c8 = cid & 7;
    union { short8 v; u16 u[8]; } uu;
    uu.v = *(const short8*)(qkv + (size_t)(s0 + s) * 3072 + 2048 + h * 64 + c8 * 8);
    for (int i = 0; i < 8; ++i) T[(c8 * 8 + i) * 72 + s] = uu.u[i];
  }
  __syncthreads();
  for (int r = 0; r < 2; ++r) {
    int cid = r * 256 + tid;
    int dd = cid >> 3, c8 = cid & 7;
    union { short8 v; u16 u[8]; } uu;
    for (int i = 0; i < 8; ++i) uu.u[i] = T[dd * 72 + c8 * 8 + i];
    *(short8*)(Vt + (size_t)(h * 64 + dd) * 4096 + s0 + c8 * 8) = uu.v;
  }
}

// C[M][N] = A[M][K]*B[N][K]^T + bias[N]; r2-verified core.
// r8: fp32 epilogue writes DIRECT from regs (was 3-barrier LDS dance).
// acc[mi][ni][r] -> C[m0+wm+mi*16+qr*4+r][n0+wn+ni*16+lq]; 16 lanes (lq)
// store 16 consecutive floats = dense 64B segments.
__global__ __launch_bounds__(256) void gemm_bt(const void* __restrict__ A,
                                               const void* __restrict__ B,
                                               const void* __restrict__ bias,
                                               void* __restrict__ C,
                                               int M, int N, int K,
                                               int lda, int ldb, int ldc,
                                               int aMay, int bMay, int outF32,
                                               const int* __restrict__ flag) {
  __shared__ __align__(16) u16 sm[128 * 132];  // 33792 B; reused by epilogue
  u16* As = sm;
  u16* Bs = sm + 128 * 64;
  const int f = flag[0];
  const int a32 = aMay && f, b32 = bMay && f;
  const int tid = threadIdx.x;
  const int w = tid >> 6, lane = tid & 63;
  const int lq = lane & 15, qr = lane >> 4;
  const int m0 = blockIdx.y * 128, n0 = blockIdx.x * 128;
  const int wm = (w >> 1) * 64, wn = (w & 1) * 64;

  f32x4 acc[4][4];
  for (int i = 0; i < 4; i++)
    for (int j = 0; j < 4; j++) acc[i][j] = (f32x4){0.f, 0.f, 0.f, 0.f};
  float bv[4];
  for (int ns = 0; ns < 4; ++ns) bv[ns] = ldf(bias, n0 + wn + ns * 16 + lq, b32);

  // hoisted staging addresses (bf16 fast path)
  const int rs = tid >> 3, cs = tid & 7;
  const u16* gA = (const u16*)A + (size_t)(m0 + rs) * lda + cs * 8;
  const u16* gB = (const u16*)B + (size_t)(n0 + rs) * ldb + cs * 8;
  u16* lA = As + ((tid & ~63) << 3);  // wave-uniform base; HW adds lane*16B
  u16* lB = Bs + ((tid & ~63) << 3);

  for (int k0 = 0; k0 < K; k0 += 64) {
    if (!(a32 | b32)) {
      for (int r = 0; r < 4; ++r) {
        __builtin_amdgcn_global_load_lds(gA + (size_t)(r * 32) * lda + k0,
                                         lA + r * 2048, 16, 0, 0);
        __builtin_amdgcn_global_load_lds(gB + (size_t)(r * 32) * ldb + k0,
                                         lB + r * 2048, 16, 0, 0);
      }
    } else {
      for (int r = 0; r < 4; ++r) {
        int cid = r * 256 + tid;
        int row = cid >> 3, c = cid & 7;
        if (a32) {
          const float* p = (const float*)A + (size_t)(m0 + row) * lda + k0 + c * 8;
          float4 v0 = *(const float4*)p, v1 = *(const float4*)(p + 4);
          union { short8 v; u16 e[8]; } t;
          t.e[0]=f2b(v0.x); t.e[1]=f2b(v0.y); t.e[2]=f2b(v0.z); t.e[3]=f2b(v0.w);
          t.e[4]=f2b(v1.x); t.e[5]=f2b(v1.y); t.e[6]=f2b(v1.z); t.e[7]=f2b(v1.w);
          *(short8*)(As + row * 64 + c * 8) = t.v;
        } else {
          *(short8*)(As + row * 64 + c * 8) =
              *(const short8*)((const u16*)A + (size_t)(m0 + row) * lda + k0 + c * 8);
        }
        if (b32) {
          const float* p = (const float*)B + (size_t)(n0 + row) * ldb + k0 + c * 8;
          float4 v0 = *(const float4*)p, v1 = *(const float4*)(p + 4);
          union { short8 v; u16 e[8]; } t;
          t.e[0]=f2b(v0.x); t.e[1]=f2b(v0.y); t.e[2]=f2b(v0.z); t.e[3]=f2b(v0.w);
          t.e[4]=f2b(v1.x); t.e[5]=f2b(v1.y); t.e[6]=f2b(v1.z); t.e[7]=f2b(v1.w);
          *(short8*)(Bs + row * 64 + c * 8) = t.v;
        } else {
          *(short8*)(Bs + row * 64 + c * 8) =
              *(const short8*)((const u16*)B + (size_t)(n0 + row) * ldb + k0 + c * 8);
        }
      }
    }
    __syncthreads();
    for (int ks = 0; ks < 2; ++ks) {
      short8 af[4], bf[4];
      const int sw = ks * 4 + qr;
      for (int i = 0; i < 4; i++) {
        af[i] = *(const short8*)(As + (wm + i * 16 + lq) * 64 + sw * 8);
        bf[i] = *(const short8*)(Bs + (wn + i * 16 + lq) * 64 + sw * 8);
      }
      for (int mi = 0; mi < 4; mi++)
        for (int ni = 0; ni < 4; ni++)
          acc[mi][ni] = __builtin_amdgcn_mfma_f32_16x16x32_bf16(
              af[mi], bf[ni], acc[mi][ni], 0, 0, 0);
    }
    __syncthreads();
  }

  if (!outF32) {
    u16* SH = sm;
    for (int mi = 0; mi < 4; mi++)
      for (int ni = 0; ni < 4; ni++)
        for (int r = 0; r < 4; ++r)
          SH[(wm + mi * 16 + qr * 4 + r) * 132 + wn + ni * 16 + lq] =
              f2b(acc[mi][ni][r] + bv[ni]);
    __syncthreads();
    for (int it = 0; it < 8; ++it) {
      int idx = it * 256 + tid;
      int row = idx >> 4, c8 = idx & 15;
      *(short8*)((u16*)C + (size_t)(m0 + row) * ldc + n0 + c8 * 8) =
          *(const short8*)(SH + row * 132 + c8 * 8);
    }
  } else {
    // direct fp32 stores (r8): no LDS roundtrip, no barriers
    float* Cf = (float*)C;
    for (int mi = 0; mi < 4; mi++) {
      int row = m0 + wm + mi * 16 + qr * 4;
      for (int r = 0; r < 4; ++r) {
        float* rp = Cf + (size_t)(row + r) * ldc + n0 + wn;
        for (int ni = 0; ni < 4; ni++)
          rp[ni * 16 + lq] = acc[mi][ni][r] + bv[ni];
      }
    }
  }
}

// Flash attention v12: r7-verified body (90.1 µs) + single-barrier combine
// epilogue (both mi in one LDS round, stride 35 floats: bank = 3i mod 32,
// bijective over 32 -> conflict-free; 4 barriers -> 1).
__global__ __launch_bounds__(512, 2) void attn_split(const u16* __restrict__ qkv,
                                                     const u16* __restrict__ Vtg,
                                                     u16* __restrict__ ctx, int ldctx) {
  __shared__ __align__(16) u16 SMEM[2][16384];
  const int tid = threadIdx.x;
  const int w = tid >> 6, lane = tid & 63;
  const int half = w >> 2, wq = w & 3, wl = w & 3;
  const int lq = lane & 15, qr = lane >> 4;
  const int qb = blockIdx.x, h = blockIdx.y;
  const int qbase = qb * 128 + wq * 32;
  const float cs = 0.18033688011112042f;  // log2(e)/8

  short8 qf[2][2];
#pragma unroll
  for (int mi = 0; mi < 2; ++mi)
#pragma unroll
    for (int ks = 0; ks < 2; ++ks)
      qf[mi][ks] = *(const short8*)(qkv + (size_t)(qbase + mi * 16 + lq) * 3072 +
                                    h * 64 + ks * 32 + qr * 8);

  f32x4 o[2][4];
#pragma unroll
  for (int mi = 0; mi < 2; ++mi)
#pragma unroll
    for (int ds = 0; ds < 4; ++ds) o[mi][ds] = (f32x4){0.f, 0.f, 0.f, 0.f};
  float lrow[2] = {0.f, 0.f};

  // staging: per-lane pre-swizzled global sources; wave-uniform LDS bases.
  const int csw = ((lane & 7) ^ (lane >> 3)) << 3;
  const int r0v = wl * 8 + (lane >> 3);  // row covered by this lane
  const u16* sK0 = qkv + (size_t)(half * 2048 + r0v) * 3072 + 1024 + h * 64 + csw;
  const u16* sK1 = sK0 + (size_t)32 * 3072;
  const u16* sV0 = Vtg + (size_t)(h * 64 + r0v) * 4096 + half * 2048 + csw;
  const u16* sV1 = sV0 + (size_t)32 * 4096;
  const int kb = half * 4096 + wl * 512;         // u16 offset, wave-uniform
  const int vb = 8192 + half * 4096 + wl * 512;

#define STAGE(buf)                                                          \
  do {                                                                      \
    u16* B_ = &SMEM[buf][0];                                                \
    __builtin_amdgcn_global_load_lds(sK0, B_ + kb, 16, 0, 0);               \
    __builtin_amdgcn_global_load_lds(sK1, B_ + kb + 2048, 16, 0, 0);        \
    __builtin_amdgcn_global_load_lds(sV0, B_ + vb, 16, 0, 0);               \
    __builtin_amdgcn_global_load_lds(sV1, B_ + vb + 2048, 16, 0, 0);        \
    sK0 += (size_t)64 * 3072; sK1 += (size_t)64 * 3072;                     \
    sV0 += 64; sV1 += 64;                                                   \
  } while (0)

  STAGE(0);
  __syncthreads();  // drain prologue loads + sync

  for (int it = 0; it < 32; ++it) {
    const int cur = it & 1;
    if (it + 1 < 32) STAGE(cur ^ 1);  // next tile; drains at loop-end barrier
    const u16* Kh = &SMEM[cur][half * 4096];
    const u16* Vh = &SMEM[cur][8192 + half * 4096];

    // QK^T (swapped: K is A-operand, Q is B-operand)
    f32x4 s[2][4];
#pragma unroll
    for (int mi = 0; mi < 2; ++mi)
#pragma unroll
      for (int ns = 0; ns < 4; ++ns) s[mi][ns] = (f32x4){0.f, 0.f, 0.f, 0.f};
#pragma unroll
    for (int ks = 0; ks < 2; ++ks) {
      short8 kf[4];
#pragma unroll
      for (int ns = 0; ns < 4; ++ns) {
        int rk = ns * 16 + lq;
        kf[ns] = *(const short8*)(Kh + rk * 64 + (((ks * 4 + qr) ^ (lq & 7)) << 3));
      }
      __builtin_amdgcn_s_setprio(1);
#pragma unroll
      for (int mi = 0; mi < 2; ++mi)
#pragma unroll
        for (int ns = 0; ns < 4; ++ns)
          s[mi][ns] = __builtin_amdgcn_mfma_f32_16x16x32_bf16(
              kf[ns], qf[mi][ks], s[mi][ns], 0, 0, 0);
      __builtin_amdgcn_s_setprio(0);
    }

    // fixed-max softmax + in-register P exchange (T12)
    short8 pf[2][2];
#pragma unroll
    for (int mi = 0; mi < 2; ++mi) {
      float lacc = 0.f;
      u32 X[4], Y[4];
#pragma unroll
      for (int ns = 0; ns < 4; ++ns) {
        float p0 = __builtin_amdgcn_exp2f(fmaf(s[mi][ns][0], cs, -12.0f));
        float p1 = __builtin_amdgcn_exp2f(fmaf(s[mi][ns][1], cs, -12.0f));
        float p2 = __builtin_amdgcn_exp2f(fmaf(s[mi][ns][2], cs, -12.0f));
        float p3 = __builtin_amdgcn_exp2f(fmaf(s[mi][ns][3], cs, -12.0f));
        lacc += (p0 + p1) + (p2 + p3);
        X[ns] = cvtpk(p0, p1);
        Y[ns] = cvtpk(p2, p3);
      }
      lrow[mi] += lacc;
#pragma unroll
      for (int ks = 0; ks < 2; ++ks) {
        u32 a0 = X[2 * ks], b0 = X[2 * ks + 1];
        u32 a1 = Y[2 * ks], b1 = Y[2 * ks + 1];
        p32swap(a0, b0); p16swap(a0, b0);
        p32swap(a1, b1); p16swap(a1, b1);
        union { u32 u[4]; short8 v; } t;
        t.u[0] = a0; t.u[1] = a1; t.u[2] = b0; t.u[3] = b1;
        pf[mi][ks] = t.v;
      }
    }

    // PV (swapped: V is A-operand, P is B-operand)
#pragma unroll
    for (int ks = 0; ks < 2; ++ks) {
      short8 vf[4];
#pragma unroll
      for (int ds = 0; ds < 4; ++ds) {
        int dv = ds * 16 + lq;
        vf[ds] = *(const short8*)(Vh + (size_t)dv * 64 +
                                  (((ks * 4 + qr) ^ (lq & 7)) << 3));
      }
      __builtin_amdgcn_s_setprio(1);
#pragma unroll
      for (int mi = 0; mi < 2; ++mi)
#pragma unroll
        for (int ds = 0; ds < 4; ++ds)
          o[mi][ds] = __builtin_amdgcn_mfma_f32_16x16x32_bf16(
              vf[ds], pf[mi][ks], o[mi][ds], 0, 0, 0);
      __builtin_amdgcn_s_setprio(0);
    }
    __syncthreads();  // compute-done + vmcnt(0) drain of next-tile loads
  }
#undef STAGE

  // in-block combine, single barrier (r8): half1 writes both mi, half0 adds.
  float* CB = (float*)&SMEM[0][0];  // 256 regions x 35 floats = 35840 B
  float* p = CB + (size_t)(wq * 64 + lane) * 35;
  if (half == 1) {
#pragma unroll
    for (int mi = 0; mi < 2; ++mi) {
#pragma unroll
      for (int ds = 0; ds < 4; ++ds)
#pragma unroll
        for (int r = 0; r < 4; ++r) p[mi * 17 + ds * 4 + r] = o[mi][ds][r];
      p[mi * 17 + 16] = lrow[mi];
    }
  }
  __syncthreads();
  if (half == 0) {
#pragma unroll
    for (int mi = 0; mi < 2; ++mi) {
#pragma unroll
      for (int ds = 0; ds < 4; ++ds)
#pragma unroll
        for (int r = 0; r < 4; ++r) o[mi][ds][r] += p[mi * 17 + ds * 4 + r];
      lrow[mi] += p[mi * 17 + 16];
    }
#pragma unroll
    for (int mi = 0; mi < 2; ++mi) {
      float l = lrow[mi];
      l += __shfl_xor(l, 16, 64);
      l += __shfl_xor(l, 32, 64);
      float linv = 1.f / fmaxf(l, 1e-30f);
      int row = qbase + mi * 16 + lq;
      u16* dst = ctx + (size_t)row * ldctx + h * 64 + qr * 4;
#pragma unroll
      for (int ds = 0; ds < 4; ++ds) {
        u32 lo = cvtpk(o[mi][ds][0] * linv, o[mi][ds][1] * linv);
        u32 hi = cvtpk(o[mi][ds][2] * linv, o[mi][ds][3] * linv);
        *(uint2*)(dst + ds * 16) = make_uint2(lo, hi);
      }
    }
  }
}

// Legacy v7 kernel (256 threads) kept ONLY for the no-workspace fallback.
__global__ __launch_bounds__(256) void attn_fused(const u16* __restrict__ qkv,
                                                  const u16* __restrict__ Vtg,
                                                  u16* __restrict__ ctx, int ldctx) {
  __shared__ u16 Ks[64 * 64];
  __shared__ u16 Vts[64 * 64];
  const int tid = threadIdx.x;
  const int w = tid >> 6, lane = tid & 63;
  const int lq = lane & 15, qr = lane >> 4;
  const int qb = blockIdx.x, h = blockIdx.y;
  const int qbase = qb * 128 + w * 32;
  const float cs = 0.18033688011112042f;

  short8 qf[2][2];
  for (int mi = 0; mi < 2; ++mi)
    for (int ks = 0; ks < 2; ++ks)
      qf[mi][ks] = *(const short8*)(qkv + (size_t)(qbase + mi * 16 + lq) * 3072 +
                                    h * 64 + ks * 32 + qr * 8);

  f32x4 o[2][4];
  for (int mi = 0; mi < 2; ++mi)
    for (int ds = 0; ds < 4; ++ds) o[mi][ds] = (f32x4){0.f, 0.f, 0.f, 0.f};
  float lrow[2] = {0.f, 0.f};

  const int c = tid & 7, r0 = tid >> 3;
  u16* dKA = Ks + r0 * 64 + ((c ^ (r0 & 7)) << 3);
  u16* dKB = dKA + 32 * 64;
  u16* dVA = Vts + r0 * 64 + ((c ^ (r0 & 7)) << 3);
  u16* dVB = dVA + 32 * 64;
  const u16* sKA = qkv + (size_t)r0 * 3072 + 1024 + h * 64 + c * 8;
  const u16* sKB = sKA + (size_t)32 * 3072;
  const u16* sVfA = qkv + (size_t)r0 * 3072 + 2048 + h * 64 + c * 8;
  const u16* sVfB = sVfA + (size_t)32 * 3072;

  short8 rKA, rKB;
  union { short8 v; u16 e[8]; } ufA, ufB;
  rKA = *(const short8*)sKA; sKA += (size_t)64 * 3072;
  rKB = *(const short8*)sKB; sKB += (size_t)64 * 3072;
  ufA.v = *(const short8*)sVfA; sVfA += (size_t)64 * 3072;
  ufB.v = *(const short8*)sVfB; sVfB += (size_t)64 * 3072;

  for (int j0 = 0; j0 < 4096; j0 += 64) {
    __syncthreads();
    *(short8*)dKA = rKA;
    *(short8*)dKB = rKB;
    {
      const int jc = r0 >> 3;
      for (int i = 0; i < 8; ++i)
        Vts[(c * 8 + i) * 64 + ((jc ^ i) << 3) + (r0 & 7)] = ufA.e[i];
    }
    {
      const int jc = (r0 + 32) >> 3;
      for (int i = 0; i < 8; ++i)
        Vts[(c * 8 + i) * 64 + ((jc ^ i) << 3) + (r0 & 7)] = ufB.e[i];
    }
    __syncthreads();

    if (j0 + 64 < 4096) {
      rKA = *(const short8*)sKA; sKA += (size_t)64 * 3072;
      rKB = *(const short8*)sKB; sKB += (size_t)64 * 3072;
      ufA.v = *(const short8*)sVfA; sVfA += (size_t)64 * 3072;
      ufB.v = *(const short8*)sVfB; sVfB += (size_t)64 * 3072;
    }

    f32x4 s[2][4];
    for (int mi = 0; mi < 2; ++mi)
      for (int ns = 0; ns < 4; ++ns) s[mi][ns] = (f32x4){0.f, 0.f, 0.f, 0.f};
    for (int ks = 0; ks < 2; ++ks) {
      short8 kf[4];
      for (int ns = 0; ns < 4; ++ns) {
        int rk = ns * 16 + lq;
        kf[ns] = *(const short8*)(Ks + rk * 64 + (((ks * 4 + qr) ^ (lq & 7)) << 3));
      }
      __builtin_amdgcn_s_setprio(1);
      for (int mi = 0; mi < 2; ++mi)
        for (int ns = 0; ns < 4; ++ns)
          s[mi][ns] = __builtin_amdgcn_mfma_f32_16x16x32_bf16(
              kf[ns], qf[mi][ks], s[mi][ns], 0, 0, 0);
      __builtin_amdgcn_s_setprio(0);
    }

    short8 pf[2][2];
#pragma unroll
    for (int mi = 0; mi < 2; ++mi) {
      float lacc = 0.f;
      u32 X[4], Y[4];
#pragma unroll
      for (int ns = 0; ns < 4; ++ns) {
        float p0 = __builtin_amdgcn_exp2f(fmaf(s[mi][ns][0], cs, -12.0f));
        float p1 = __builtin_amdgcn_exp2f(fmaf(s[mi][ns][1], cs, -12.0f));
        float p2 = __builtin_amdgcn_exp2f(fmaf(s[mi][ns][2], cs, -12.0f));
        float p3 = __builtin_amdgcn_exp2f(fmaf(s[mi][ns][3], cs, -12.0f));
        lacc += (p0 + p1) + (p2 + p3);
        X[ns] = cvtpk(p0, p1);
        Y[ns] = cvtpk(p2, p3);
      }
      lrow[mi] += lacc;
#pragma unroll
      for (int ks = 0; ks < 2; ++ks) {
        u32 a0 = X[2 * ks], b0 = X[2 * ks + 1];
        u32 a1 = Y[2 * ks], b1 = Y[2 * ks + 1];
        p32swap(a0, b0); p16swap(a0, b0);
        p32swap(a1, b1); p16swap(a1, b1);
        union { u32 u[4]; short8 v; } t;
        t.u[0] = a0; t.u[1] = a1; t.u[2] = b0; t.u[3] = b1;
        pf[mi][ks] = t.v;
      }
    }

    for (int ks = 0; ks < 2; ++ks) {
      short8 vf[4];
      for (int ds = 0; ds < 4; ++ds) {
        int dv = ds * 16 + lq;
        vf[ds] = *(const short8*)(Vts + (size_t)dv * 64 +
                                  (((ks * 4 + qr) ^ (lq & 7)) << 3));
      }
      __builtin_amdgcn_s_setprio(1);
      for (int mi = 0; mi < 2; ++mi)
        for (int ds = 0; ds < 4; ++ds)
          o[mi][ds] = __builtin_amdgcn_mfma_f32_16x16x32_bf16(
              vf[ds], pf[mi][ks], o[mi][ds], 0, 0, 0);
      __builtin_amdgcn_s_setprio(0);
    }
  }

  for (int mi = 0; mi < 2; ++mi) {
    float l = lrow[mi];
    l += __shfl_xor(l, 16, 64);
    l += __shfl_xor(l, 32, 64);
    float linv = 1.f / fmaxf(l, 1e-30f);
    int row = qbase + mi * 16 + lq;
    u16* dst = ctx + (size_t)row * ldctx + h * 64 + qr * 4;
    for (int ds = 0; ds < 4; ++ds) {
      u32 lo = cvtpk(o[mi][ds][0] * linv, o[mi][ds][1] * linv);
      u32 hi = cvtpk(o[mi][ds][2] * linv, o[mi][ds][3] * linv);
      *(uint2*)(dst + ds * 16) = make_uint2(lo, hi);
    }
  }
}

extern "C" void kernel_launch(void* const* d_in, const int* in_sizes, int n_in,
                              void* d_out, int out_size, void* d_ws, size_t ws_size,
                              hipStream_t stream) {
  float* out = (float*)d_out;  // reference output dtype is fp32

  const void *px = nullptr, *pwq = nullptr, *pbq = nullptr, *pwo = nullptr, *pbo = nullptr;
  if (n_in == 5) {
    for (int i = 0; i < 5; ++i) {
      switch (in_sizes[i]) {
        case 4194304: px = d_in[i]; break;
        case 3145728: pwq = d_in[i]; break;
        case 3072:    pbq = d_in[i]; break;
        case 1048576: pwo = d_in[i]; break;
        case 1024:    pbo = d_in[i]; break;
        default: break;
      }
    }
  }
  if (!px || !pwq || !pbq || !pwo || !pbo) {
    px = d_in[0]; pwq = d_in[1]; pbq = d_in[2]; pwo = d_in[3]; pbo = d_in[4];
  }

  int* flag = (int*)d_ws;
  u16* qkv = (u16*)((char*)d_ws + 64);
  u16* ctx = qkv;  // aliases dead Q-region (row stride 3072); race-free per block

  const size_t nQKV = (size_t)4096 * 3072;
  const size_t nVt = (size_t)16 * 64 * 4096;
  const size_t nx = 4194304, nwq = 3145728, nwo = 1048576;
  u16* Vtg = qkv + nQKV;
  const size_t need_vt = 64 + (nQKV + nVt) * 2;
  const size_t need_full = need_vt + (nx + nwq + 4096 + nwo + 1024) * 2;

  if (ws_size >= need_full) {
    u16* xb    = Vtg + nVt;
    u16* wqkvb = xb + nx;
    u16* bqkvb = wqkvb + nwq;
    u16* wob   = bqkvb + 4096;
    u16* bob   = wob + nwo;
    convert_all<<<4098, 256, 0, stream>>>(px, pwq, pbq, pwo, pbo,
                                          xb, wqkvb, bqkvb, wob, bob);

    // MEASUREMENT PROBE (r8): gemm1 launched twice — identical deterministic
    // writes; total-time delta vs r7 measures gemm1_dur. Remove next round.
    gemm_bt<<<dim3(24, 32), 256, 0, stream>>>(xb, wqkvb, bqkvb, qkv,
                                              4096, 3072, 1024, 1024, 1024, 3072,
                                              0, 0, 0, flag);
    gemm_bt<<<dim3(24, 32), 256, 0, stream>>>(xb, wqkvb, bqkvb, qkv,
                                              4096, 3072, 1024, 1024, 1024, 3072,
                                              0, 0, 0, flag);
    transpose_v<<<dim3(64, 16), 256, 0, stream>>>(qkv, Vtg);
    attn_split<<<dim3(32, 16), 512, 0, stream>>>(qkv, Vtg, ctx, 3072);
    gemm_bt<<<dim3(8, 32), 256, 0, stream>>>(ctx, wob, bob, out,
                                             4096, 1024, 1024, 3072, 1024, 1024,
                                             0, 0, 1, flag);
  } else if (ws_size >= need_vt) {
    detect_dtype<<<1, 256, 0, stream>>>((const u16*)px, flag);
    gemm_bt<<<dim3(24, 32), 256, 0, stream>>>(px, pwq, pbq, qkv,
                                              4096, 3072, 1024, 1024, 1024, 3072,
                                              1, 1, 0, flag);
    transpose_v<<<dim3(64, 16), 256, 0, stream>>>(qkv, Vtg);
    attn_split<<<dim3(32, 16), 512, 0, stream>>>(qkv, Vtg, ctx, 3072);
    gemm_bt<<<dim3(8, 32), 256, 0, stream>>>(ctx, pwo, pbo, out,
                                             4096, 1024, 1024, 3072, 1024, 1024,
                                             0, 1, 1, flag);
  } else {
    detect_dtype<<<1, 256, 0, stream>>>((const u16*)px, flag);
    gemm_bt<<<dim3(24, 32), 256, 0, stream>>>(px, pwq, pbq, qkv,
                                              4096, 3072, 1024, 1024, 1024, 3072,
                                              1, 1, 0, flag);
    attn_fused<<<dim3(32, 16), 256, 0, stream>>>(qkv, (const u16*)nullptr, ctx, 3072);
    gemm_bt<<<dim3(8, 32), 256, 0, stream>>>(ctx, pwo, pbo, out,
                                             4096, 1024, 1024, 3072, 1024, 1024,
                                             0, 1, 1, flag);
  }
}

// Round 9
// 260.058 us; speedup vs baseline: 1.2176x; 1.2176x over previous
//
#include <hip/hip_runtime.h>

typedef unsigned short u16;
typedef unsigned int u32;
typedef __attribute__((ext_vector_type(8))) short short8;
typedef __attribute__((ext_vector_type(4))) float f32x4;

__device__ __forceinline__ u16 f2b(float f) {  // RNE
  union { float f; unsigned u; } v; v.f = f;
  unsigned r = (v.u + 0x7FFFu + ((v.u >> 16) & 1u)) >> 16;
  return (u16)r;
}
__device__ __forceinline__ float b2f(u16 b) {
  union { unsigned u; float f; } v; v.u = ((unsigned)b) << 16;
  return v.f;
}
// Single-instruction packed f32->bf16 (RNE). T12 recipe: no builtin on gfx950.
__device__ __forceinline__ u32 cvtpk(float a, float b) {
  u32 r;
  asm("v_cvt_pk_bf16_f32 %0, %1, %2" : "=v"(r) : "v"(a), "v"(b));
  return r;
}
// Cross-lane row swaps (gfx950). Both operands are read-write.
__device__ __forceinline__ void p32swap(u32& a, u32& b) {
  asm("v_permlane32_swap_b32 %0, %1" : "+v"(a), "+v"(b));
}
__device__ __forceinline__ void p16swap(u32& a, u32& b) {
  asm("v_permlane16_swap_b32 %0, %1" : "+v"(a), "+v"(b));
}
__device__ __forceinline__ float ldf(const void* p, size_t i, int f32) {
  return f32 ? ((const float*)p)[i] : b2f(((const u16*)p)[i]);
}

// fp32 vs bf16 input detector (HW-verified; fp32 on this harness).
// Kept for the reduced-workspace fallback paths.
__global__ __launch_bounds__(256) void detect_dtype(const u16* __restrict__ x,
                                                    int* __restrict__ flag) {
  __shared__ int cnt;
  if (threadIdx.x == 0) cnt = 0;
  __syncthreads();
  int local = 0;
  for (int p = threadIdx.x; p < 512; p += 256) {
    int e = (x[2 * p] >> 7) & 0xFF;
    if (e >= 0xC0) local++;
  }
  atomicAdd(&cnt, local);
  __syncthreads();
  if (threadIdx.x == 0) flag[0] = (cnt >= 16) ? 1 : 0;
}

// Fused one-time fp32->bf16 convert of all 5 tensors (1 launch, self-detecting).
__global__ __launch_bounds__(256) void convert_all(
    const void* __restrict__ px, const void* __restrict__ pwq,
    const void* __restrict__ pbq, const void* __restrict__ pwo,
    const void* __restrict__ pbo, u16* __restrict__ xb,
    u16* __restrict__ wqkvb, u16* __restrict__ bqkvb, u16* __restrict__ wob,
    u16* __restrict__ bob) {
  __shared__ int sf;
  if (threadIdx.x == 0) sf = 0;
  __syncthreads();
  {
    const u16* xr = (const u16*)px;
    int local = 0;
    for (int p = threadIdx.x; p < 512; p += 256) {
      int e = (xr[2 * p] >> 7) & 0xFF;
      if (e >= 0xC0) local++;
    }
    atomicAdd(&sf, local);
  }
  __syncthreads();
  const int isf32 = (sf >= 16);

  int i = blockIdx.x * 256 + threadIdx.x;
  const void* in; u16* out; size_t g;
  if (i < 524288)       { in = px;  out = xb;    g = (size_t)i; }
  else if (i < 917504)  { in = pwq; out = wqkvb; g = (size_t)(i - 524288); }
  else if (i < 917888)  { in = pbq; out = bqkvb; g = (size_t)(i - 917504); }
  else if (i < 1048960) { in = pwo; out = wob;   g = (size_t)(i - 917888); }
  else                  { in = pbo; out = bob;   g = (size_t)(i - 1048960); }
  size_t base = g * 8;
  if (isf32) {
    const float* p = (const float*)in + base;
    float4 v0 = *(const float4*)p, v1 = *(const float4*)(p + 4);
    union { short8 v; u16 e[8]; } t;
    t.e[0]=f2b(v0.x); t.e[1]=f2b(v0.y); t.e[2]=f2b(v0.z); t.e[3]=f2b(v0.w);
    t.e[4]=f2b(v1.x); t.e[5]=f2b(v1.y); t.e[6]=f2b(v1.z); t.e[7]=f2b(v1.w);
    *(short8*)(out + base) = t.v;
  } else {
    *(short8*)(out + base) = *(const short8*)((const u16*)in + base);
  }
}

// qkv[n][3072] V-cols -> Vtg[h][64][4096]  (HW-verified)
__global__ __launch_bounds__(256) void transpose_v(const u16* __restrict__ qkv,
                                                   u16* __restrict__ Vt) {
  __shared__ u16 T[64 * 72];
  const int tid = threadIdx.x;
  const int h = blockIdx.y;
  const int s0 = blockIdx.x * 64;
  for (int r = 0; r < 2; ++r) {
    int cid = r * 256 + tid;
    int s = cid >> 3, c8 = cid & 7;
    union { short8 v; u16 u[8]; } uu;
    uu.v = *(const short8*)(qkv + (size_t)(s0 + s) * 3072 + 2048 + h * 64 + c8 * 8);
    for (int i = 0; i < 8; ++i) T[(c8 * 8 + i) * 72 + s] = uu.u[i];
  }
  __syncthreads();
  for (int r = 0; r < 2; ++r) {
    int cid = r * 256 + tid;
    int dd = cid >> 3, c8 = cid & 7;
    union { short8 v; u16 u[8]; } uu;
    for (int i = 0; i < 8; ++i) uu.u[i] = T[dd * 72 + c8 * 8 + i];
    *(short8*)(Vt + (size_t)(h * 64 + dd) * 4096 + s0 + c8 * 8) = uu.v;
  }
}

// C[M][N] = A[M][K]*B[N][K]^T + bias[N]; r2-verified core; r8 direct fp32
// epilogue. Used for gemm1 (bf16 out) and all fallback paths.
__global__ __launch_bounds__(256) void gemm_bt(const void* __restrict__ A,
                                               const void* __restrict__ B,
                                               const void* __restrict__ bias,
                                               void* __restrict__ C,
                                               int M, int N, int K,
                                               int lda, int ldb, int ldc,
                                               int aMay, int bMay, int outF32,
                                               const int* __restrict__ flag) {
  __shared__ __align__(16) u16 sm[128 * 132];  // 33792 B; reused by epilogue
  u16* As = sm;
  u16* Bs = sm + 128 * 64;
  const int f = flag[0];
  const int a32 = aMay && f, b32 = bMay && f;
  const int tid = threadIdx.x;
  const int w = tid >> 6, lane = tid & 63;
  const int lq = lane & 15, qr = lane >> 4;
  const int m0 = blockIdx.y * 128, n0 = blockIdx.x * 128;
  const int wm = (w >> 1) * 64, wn = (w & 1) * 64;

  f32x4 acc[4][4];
  for (int i = 0; i < 4; i++)
    for (int j = 0; j < 4; j++) acc[i][j] = (f32x4){0.f, 0.f, 0.f, 0.f};
  float bv[4];
  for (int ns = 0; ns < 4; ++ns) bv[ns] = ldf(bias, n0 + wn + ns * 16 + lq, b32);

  // hoisted staging addresses (bf16 fast path)
  const int rs = tid >> 3, cs = tid & 7;
  const u16* gA = (const u16*)A + (size_t)(m0 + rs) * lda + cs * 8;
  const u16* gB = (const u16*)B + (size_t)(n0 + rs) * ldb + cs * 8;
  u16* lA = As + ((tid & ~63) << 3);  // wave-uniform base; HW adds lane*16B
  u16* lB = Bs + ((tid & ~63) << 3);

  for (int k0 = 0; k0 < K; k0 += 64) {
    if (!(a32 | b32)) {
      for (int r = 0; r < 4; ++r) {
        __builtin_amdgcn_global_load_lds(gA + (size_t)(r * 32) * lda + k0,
                                         lA + r * 2048, 16, 0, 0);
        __builtin_amdgcn_global_load_lds(gB + (size_t)(r * 32) * ldb + k0,
                                         lB + r * 2048, 16, 0, 0);
      }
    } else {
      for (int r = 0; r < 4; ++r) {
        int cid = r * 256 + tid;
        int row = cid >> 3, c = cid & 7;
        if (a32) {
          const float* p = (const float*)A + (size_t)(m0 + row) * lda + k0 + c * 8;
          float4 v0 = *(const float4*)p, v1 = *(const float4*)(p + 4);
          union { short8 v; u16 e[8]; } t;
          t.e[0]=f2b(v0.x); t.e[1]=f2b(v0.y); t.e[2]=f2b(v0.z); t.e[3]=f2b(v0.w);
          t.e[4]=f2b(v1.x); t.e[5]=f2b(v1.y); t.e[6]=f2b(v1.z); t.e[7]=f2b(v1.w);
          *(short8*)(As + row * 64 + c * 8) = t.v;
        } else {
          *(short8*)(As + row * 64 + c * 8) =
              *(const short8*)((const u16*)A + (size_t)(m0 + row) * lda + k0 + c * 8);
        }
        if (b32) {
          const float* p = (const float*)B + (size_t)(n0 + row) * ldb + k0 + c * 8;
          float4 v0 = *(const float4*)p, v1 = *(const float4*)(p + 4);
          union { short8 v; u16 e[8]; } t;
          t.e[0]=f2b(v0.x); t.e[1]=f2b(v0.y); t.e[2]=f2b(v0.z); t.e[3]=f2b(v0.w);
          t.e[4]=f2b(v1.x); t.e[5]=f2b(v1.y); t.e[6]=f2b(v1.z); t.e[7]=f2b(v1.w);
          *(short8*)(Bs + row * 64 + c * 8) = t.v;
        } else {
          *(short8*)(Bs + row * 64 + c * 8) =
              *(const short8*)((const u16*)B + (size_t)(n0 + row) * ldb + k0 + c * 8);
        }
      }
    }
    __syncthreads();
    for (int ks = 0; ks < 2; ++ks) {
      short8 af[4], bf[4];
      const int sw = ks * 4 + qr;
      for (int i = 0; i < 4; i++) {
        af[i] = *(const short8*)(As + (wm + i * 16 + lq) * 64 + sw * 8);
        bf[i] = *(const short8*)(Bs + (wn + i * 16 + lq) * 64 + sw * 8);
      }
      for (int mi = 0; mi < 4; mi++)
        for (int ni = 0; ni < 4; ni++)
          acc[mi][ni] = __builtin_amdgcn_mfma_f32_16x16x32_bf16(
              af[mi], bf[ni], acc[mi][ni], 0, 0, 0);
    }
    __syncthreads();
  }

  if (!outF32) {
    u16* SH = sm;
    for (int mi = 0; mi < 4; mi++)
      for (int ni = 0; ni < 4; ni++)
        for (int r = 0; r < 4; ++r)
          SH[(wm + mi * 16 + qr * 4 + r) * 132 + wn + ni * 16 + lq] =
              f2b(acc[mi][ni][r] + bv[ni]);
    __syncthreads();
    for (int it = 0; it < 8; ++it) {
      int idx = it * 256 + tid;
      int row = idx >> 4, c8 = idx & 15;
      *(short8*)((u16*)C + (size_t)(m0 + row) * ldc + n0 + c8 * 8) =
          *(const short8*)(SH + row * 132 + c8 * 8);
    }
  } else {
    // direct fp32 stores (r8): no LDS roundtrip, no barriers
    float* Cf = (float*)C;
    for (int mi = 0; mi < 4; mi++) {
      int row = m0 + wm + mi * 16 + qr * 4;
      for (int r = 0; r < 4; ++r) {
        float* rp = Cf + (size_t)(row + r) * ldc + n0 + wn;
        for (int ni = 0; ni < 4; ni++)
          rp[ni * 16 + lq] = acc[mi][ni][r] + bv[ni];
      }
    }
  }
}

// gemm2 K-split kernel (r9): C[M][N] = A·B^T + bias, fp32 out, bf16 inputs.
// gemm2's grid (8,32)=256 blocks was 1 block/CU = 1 wave/SIMD — latency-
// exposed (the r3 fused4 failure mode). Fix: 512-thread blocks; waves 0-3
// compute K in [0,512), waves 4-7 K in [512,1024), each half staging into
// its own 32KB LDS region -> 16 waves/CU = 4 waves/SIMD. Partials combined
// through the (dead) staging LDS in 2 rounds of stride-33 regions (bank =
// (ht+j)%32, conflict-free); bias added once by half 0; direct fp32 stores.
__global__ __launch_bounds__(512, 2) void gemm_bt_ks(const u16* __restrict__ A,
                                                     const u16* __restrict__ B,
                                                     const u16* __restrict__ bias,
                                                     float* __restrict__ C,
                                                     int K, int lda, int ldb, int ldc) {
  __shared__ __align__(16) u16 sm[2][16384];  // per-half: A tile | B tile
  const int tid = threadIdx.x;
  const int w = tid >> 6, lane = tid & 63;
  const int half = w >> 2, wq = w & 3;
  const int ht = tid & 255;
  const int lq = lane & 15, qr = lane >> 4;
  const int m0 = blockIdx.y * 128, n0 = blockIdx.x * 128;
  const int wm = (wq >> 1) * 64, wn = (wq & 1) * 64;
  const int kh = K >> 1;

  u16* As = &sm[half][0];
  u16* Bs = &sm[half][8192];

  f32x4 acc[4][4];
  for (int i = 0; i < 4; i++)
    for (int j = 0; j < 4; j++) acc[i][j] = (f32x4){0.f, 0.f, 0.f, 0.f};
  float bv[4];
  for (int ns = 0; ns < 4; ++ns) bv[ns] = b2f(bias[n0 + wn + ns * 16 + lq]);

  const int rs = ht >> 3, cs = ht & 7;
  const u16* gA = A + (size_t)(m0 + rs) * lda + half * kh + cs * 8;
  const u16* gB = B + (size_t)(n0 + rs) * ldb + half * kh + cs * 8;
  u16* lA = As + ((ht & ~63) << 3);  // wave-uniform base; HW adds lane*16B
  u16* lB = Bs + ((ht & ~63) << 3);

  for (int k0 = 0; k0 < kh; k0 += 64) {
    for (int r = 0; r < 4; ++r) {
      __builtin_amdgcn_global_load_lds(gA + (size_t)(r * 32) * lda + k0,
                                       lA + r * 2048, 16, 0, 0);
      __builtin_amdgcn_global_load_lds(gB + (size_t)(r * 32) * ldb + k0,
                                       lB + r * 2048, 16, 0, 0);
    }
    __syncthreads();
    for (int ks = 0; ks < 2; ++ks) {
      short8 af[4], bf[4];
      const int sw = ks * 4 + qr;
      for (int i = 0; i < 4; i++) {
        af[i] = *(const short8*)(As + (wm + i * 16 + lq) * 64 + sw * 8);
        bf[i] = *(const short8*)(Bs + (wn + i * 16 + lq) * 64 + sw * 8);
      }
      for (int mi = 0; mi < 4; mi++)
        for (int ni = 0; ni < 4; ni++)
          acc[mi][ni] = __builtin_amdgcn_mfma_f32_16x16x32_bf16(
              af[mi], bf[ni], acc[mi][ni], 0, 0, 0);
    }
    __syncthreads();
  }

  // cross-half combine: 2 rounds x 2 mi (32 floats/thread, stride-33 regions)
  float* CB = (float*)&sm[0][0];
  float* p = CB + (size_t)ht * 33;
  for (int t = 0; t < 2; ++t) {
    if (half == 1) {
      for (int u = 0; u < 2; ++u)
        for (int ni = 0; ni < 4; ++ni)
          for (int r = 0; r < 4; ++r)
            p[u * 16 + ni * 4 + r] = acc[2 * t + u][ni][r];
    }
    __syncthreads();
    if (half == 0) {
      for (int u = 0; u < 2; ++u)
        for (int ni = 0; ni < 4; ++ni)
          for (int r = 0; r < 4; ++r)
            acc[2 * t + u][ni][r] += p[u * 16 + ni * 4 + r];
    }
    __syncthreads();
  }

  if (half == 0) {
    for (int mi = 0; mi < 4; mi++) {
      int row = m0 + wm + mi * 16 + qr * 4;
      for (int r = 0; r < 4; ++r) {
        float* rp = C + (size_t)(row + r) * ldc + n0 + wn;
        for (int ni = 0; ni < 4; ni++)
          rp[ni * 16 + lq] = acc[mi][ni][r] + bv[ni];
      }
    }
  }
}

// Flash attention (r7-verified, 90.1 µs): KV-split + glds staging + dbuf +
// one barrier/iter; r7 combine epilogue (two stride-17 rounds) RESTORED —
// r8's single-barrier stride-35 variant regressed 90.1->96.7.
__global__ __launch_bounds__(512, 2) void attn_split(const u16* __restrict__ qkv,
                                                     const u16* __restrict__ Vtg,
                                                     u16* __restrict__ ctx, int ldctx) {
  __shared__ __align__(16) u16 SMEM[2][16384];
  const int tid = threadIdx.x;
  const int w = tid >> 6, lane = tid & 63;
  const int half = w >> 2, wq = w & 3, wl = w & 3;
  const int lq = lane & 15, qr = lane >> 4;
  const int qb = blockIdx.x, h = blockIdx.y;
  const int qbase = qb * 128 + wq * 32;
  const float cs = 0.18033688011112042f;  // log2(e)/8

  short8 qf[2][2];
#pragma unroll
  for (int mi = 0; mi < 2; ++mi)
#pragma unroll
    for (int ks = 0; ks < 2; ++ks)
      qf[mi][ks] = *(const short8*)(qkv + (size_t)(qbase + mi * 16 + lq) * 3072 +
                                    h * 64 + ks * 32 + qr * 8);

  f32x4 o[2][4];
#pragma unroll
  for (int mi = 0; mi < 2; ++mi)
#pragma unroll
    for (int ds = 0; ds < 4; ++ds) o[mi][ds] = (f32x4){0.f, 0.f, 0.f, 0.f};
  float lrow[2] = {0.f, 0.f};

  // staging: per-lane pre-swizzled global sources; wave-uniform LDS bases.
  const int csw = ((lane & 7) ^ (lane >> 3)) << 3;
  const int r0v = wl * 8 + (lane >> 3);  // row covered by this lane
  const u16* sK0 = qkv + (size_t)(half * 2048 + r0v) * 3072 + 1024 + h * 64 + csw;
  const u16* sK1 = sK0 + (size_t)32 * 3072;
  const u16* sV0 = Vtg + (size_t)(h * 64 + r0v) * 4096 + half * 2048 + csw;
  const u16* sV1 = sV0 + (size_t)32 * 4096;
  const int kb = half * 4096 + wl * 512;         // u16 offset, wave-uniform
  const int vb = 8192 + half * 4096 + wl * 512;

#define STAGE(buf)                                                          \
  do {                                                                      \
    u16* B_ = &SMEM[buf][0];                                                \
    __builtin_amdgcn_global_load_lds(sK0, B_ + kb, 16, 0, 0);               \
    __builtin_amdgcn_global_load_lds(sK1, B_ + kb + 2048, 16, 0, 0);        \
    __builtin_amdgcn_global_load_lds(sV0, B_ + vb, 16, 0, 0);               \
    __builtin_amdgcn_global_load_lds(sV1, B_ + vb + 2048, 16, 0, 0);        \
    sK0 += (size_t)64 * 3072; sK1 += (size_t)64 * 3072;                     \
    sV0 += 64; sV1 += 64;                                                   \
  } while (0)

  STAGE(0);
  __syncthreads();  // drain prologue loads + sync

  for (int it = 0; it < 32; ++it) {
    const int cur = it & 1;
    if (it + 1 < 32) STAGE(cur ^ 1);  // next tile; drains at loop-end barrier
    const u16* Kh = &SMEM[cur][half * 4096];
    const u16* Vh = &SMEM[cur][8192 + half * 4096];

    // QK^T (swapped: K is A-operand, Q is B-operand)
    f32x4 s[2][4];
#pragma unroll
    for (int mi = 0; mi < 2; ++mi)
#pragma unroll
      for (int ns = 0; ns < 4; ++ns) s[mi][ns] = (f32x4){0.f, 0.f, 0.f, 0.f};
#pragma unroll
    for (int ks = 0; ks < 2; ++ks) {
      short8 kf[4];
#pragma unroll
      for (int ns = 0; ns < 4; ++ns) {
        int rk = ns * 16 + lq;
        kf[ns] = *(const short8*)(Kh + rk * 64 + (((ks * 4 + qr) ^ (lq & 7)) << 3));
      }
      __builtin_amdgcn_s_setprio(1);
#pragma unroll
      for (int mi = 0; mi < 2; ++mi)
#pragma unroll
        for (int ns = 0; ns < 4; ++ns)
          s[mi][ns] = __builtin_amdgcn_mfma_f32_16x16x32_bf16(
              kf[ns], qf[mi][ks], s[mi][ns], 0, 0, 0);
      __builtin_amdgcn_s_setprio(0);
    }

    // fixed-max softmax + in-register P exchange (T12)
    short8 pf[2][2];
#pragma unroll
    for (int mi = 0; mi < 2; ++mi) {
      float lacc = 0.f;
      u32 X[4], Y[4];
#pragma unroll
      for (int ns = 0; ns < 4; ++ns) {
        float p0 = __builtin_amdgcn_exp2f(fmaf(s[mi][ns][0], cs, -12.0f));
        float p1 = __builtin_amdgcn_exp2f(fmaf(s[mi][ns][1], cs, -12.0f));
        float p2 = __builtin_amdgcn_exp2f(fmaf(s[mi][ns][2], cs, -12.0f));
        float p3 = __builtin_amdgcn_exp2f(fmaf(s[mi][ns][3], cs, -12.0f));
        lacc += (p0 + p1) + (p2 + p3);
        X[ns] = cvtpk(p0, p1);
        Y[ns] = cvtpk(p2, p3);
      }
      lrow[mi] += lacc;
#pragma unroll
      for (int ks = 0; ks < 2; ++ks) {
        u32 a0 = X[2 * ks], b0 = X[2 * ks + 1];
        u32 a1 = Y[2 * ks], b1 = Y[2 * ks + 1];
        p32swap(a0, b0); p16swap(a0, b0);
        p32swap(a1, b1); p16swap(a1, b1);
        union { u32 u[4]; short8 v; } t;
        t.u[0] = a0; t.u[1] = a1; t.u[2] = b0; t.u[3] = b1;
        pf[mi][ks] = t.v;
      }
    }

    // PV (swapped: V is A-operand, P is B-operand)
#pragma unroll
    for (int ks = 0; ks < 2; ++ks) {
      short8 vf[4];
#pragma unroll
      for (int ds = 0; ds < 4; ++ds) {
        int dv = ds * 16 + lq;
        vf[ds] = *(const short8*)(Vh + (size_t)dv * 64 +
                                  (((ks * 4 + qr) ^ (lq & 7)) << 3));
      }
      __builtin_amdgcn_s_setprio(1);
#pragma unroll
      for (int mi = 0; mi < 2; ++mi)
#pragma unroll
        for (int ds = 0; ds < 4; ++ds)
          o[mi][ds] = __builtin_amdgcn_mfma_f32_16x16x32_bf16(
              vf[ds], pf[mi][ks], o[mi][ds], 0, 0, 0);
      __builtin_amdgcn_s_setprio(0);
    }
    __syncthreads();  // compute-done + vmcnt(0) drain of next-tile loads
  }
#undef STAGE

  // in-block combine (r7-verified): per-mi rounds, stride-17 fp32 regions.
  float* CB = (float*)&SMEM[0][0];
#pragma unroll
  for (int mi = 0; mi < 2; ++mi) {
    float* p = CB + (size_t)(wq * 64 + lane) * 17;
    if (half == 1) {
#pragma unroll
      for (int ds = 0; ds < 4; ++ds) {
        p[ds * 4 + 0] = o[mi][ds][0];
        p[ds * 4 + 1] = o[mi][ds][1];
        p[ds * 4 + 2] = o[mi][ds][2];
        p[ds * 4 + 3] = o[mi][ds][3];
      }
      p[16] = lrow[mi];
    }
    __syncthreads();
    if (half == 0) {
#pragma unroll
      for (int ds = 0; ds < 4; ++ds) {
        o[mi][ds][0] += p[ds * 4 + 0];
        o[mi][ds][1] += p[ds * 4 + 1];
        o[mi][ds][2] += p[ds * 4 + 2];
        o[mi][ds][3] += p[ds * 4 + 3];
      }
      lrow[mi] += p[16];
    }
    __syncthreads();
  }

  if (half == 0) {
#pragma unroll
    for (int mi = 0; mi < 2; ++mi) {
      float l = lrow[mi];
      l += __shfl_xor(l, 16, 64);
      l += __shfl_xor(l, 32, 64);
      float linv = 1.f / fmaxf(l, 1e-30f);
      int row = qbase + mi * 16 + lq;
      u16* dst = ctx + (size_t)row * ldctx + h * 64 + qr * 4;
#pragma unroll
      for (int ds = 0; ds < 4; ++ds) {
        u32 lo = cvtpk(o[mi][ds][0] * linv, o[mi][ds][1] * linv);
        u32 hi = cvtpk(o[mi][ds][2] * linv, o[mi][ds][3] * linv);
        *(uint2*)(dst + ds * 16) = make_uint2(lo, hi);
      }
    }
  }
}

// Legacy v7 kernel (256 threads) kept ONLY for the no-workspace fallback.
__global__ __launch_bounds__(256) void attn_fused(const u16* __restrict__ qkv,
                                                  const u16* __restrict__ Vtg,
                                                  u16* __restrict__ ctx, int ldctx) {
  __shared__ u16 Ks[64 * 64];
  __shared__ u16 Vts[64 * 64];
  const int tid = threadIdx.x;
  const int w = tid >> 6, lane = tid & 63;
  const int lq = lane & 15, qr = lane >> 4;
  const int qb = blockIdx.x, h = blockIdx.y;
  const int qbase = qb * 128 + w * 32;
  const float cs = 0.18033688011112042f;

  short8 qf[2][2];
  for (int mi = 0; mi < 2; ++mi)
    for (int ks = 0; ks < 2; ++ks)
      qf[mi][ks] = *(const short8*)(qkv + (size_t)(qbase + mi * 16 + lq) * 3072 +
                                    h * 64 + ks * 32 + qr * 8);

  f32x4 o[2][4];
  for (int mi = 0; mi < 2; ++mi)
    for (int ds = 0; ds < 4; ++ds) o[mi][ds] = (f32x4){0.f, 0.f, 0.f, 0.f};
  float lrow[2] = {0.f, 0.f};

  const int c = tid & 7, r0 = tid >> 3;
  u16* dKA = Ks + r0 * 64 + ((c ^ (r0 & 7)) << 3);
  u16* dKB = dKA + 32 * 64;
  const u16* sKA = qkv + (size_t)r0 * 3072 + 1024 + h * 64 + c * 8;
  const u16* sKB = sKA + (size_t)32 * 3072;
  const u16* sVfA = qkv + (size_t)r0 * 3072 + 2048 + h * 64 + c * 8;
  const u16* sVfB = sVfA + (size_t)32 * 3072;

  short8 rKA, rKB;
  union { short8 v; u16 e[8]; } ufA, ufB;
  rKA = *(const short8*)sKA; sKA += (size_t)64 * 3072;
  rKB = *(const short8*)sKB; sKB += (size_t)64 * 3072;
  ufA.v = *(const short8*)sVfA; sVfA += (size_t)64 * 3072;
  ufB.v = *(const short8*)sVfB; sVfB += (size_t)64 * 3072;

  for (int j0 = 0; j0 < 4096; j0 += 64) {
    __syncthreads();
    *(short8*)dKA = rKA;
    *(short8*)dKB = rKB;
    {
      const int jc = r0 >> 3;
      for (int i = 0; i < 8; ++i)
        Vts[(c * 8 + i) * 64 + ((jc ^ i) << 3) + (r0 & 7)] = ufA.e[i];
    }
    {
      const int jc = (r0 + 32) >> 3;
      for (int i = 0; i < 8; ++i)
        Vts[(c * 8 + i) * 64 + ((jc ^ i) << 3) + (r0 & 7)] = ufB.e[i];
    }
    __syncthreads();

    if (j0 + 64 < 4096) {
      rKA = *(const short8*)sKA; sKA += (size_t)64 * 3072;
      rKB = *(const short8*)sKB; sKB += (size_t)64 * 3072;
      ufA.v = *(const short8*)sVfA; sVfA += (size_t)64 * 3072;
      ufB.v = *(const short8*)sVfB; sVfB += (size_t)64 * 3072;
    }

    f32x4 s[2][4];
    for (int mi = 0; mi < 2; ++mi)
      for (int ns = 0; ns < 4; ++ns) s[mi][ns] = (f32x4){0.f, 0.f, 0.f, 0.f};
    for (int ks = 0; ks < 2; ++ks) {
      short8 kf[4];
      for (int ns = 0; ns < 4; ++ns) {
        int rk = ns * 16 + lq;
        kf[ns] = *(const short8*)(Ks + rk * 64 + (((ks * 4 + qr) ^ (lq & 7)) << 3));
      }
      __builtin_amdgcn_s_setprio(1);
      for (int mi = 0; mi < 2; ++mi)
        for (int ns = 0; ns < 4; ++ns)
          s[mi][ns] = __builtin_amdgcn_mfma_f32_16x16x32_bf16(
              kf[ns], qf[mi][ks], s[mi][ns], 0, 0, 0);
      __builtin_amdgcn_s_setprio(0);
    }

    short8 pf[2][2];
#pragma unroll
    for (int mi = 0; mi < 2; ++mi) {
      float lacc = 0.f;
      u32 X[4], Y[4];
#pragma unroll
      for (int ns = 0; ns < 4; ++ns) {
        float p0 = __builtin_amdgcn_exp2f(fmaf(s[mi][ns][0], cs, -12.0f));
        float p1 = __builtin_amdgcn_exp2f(fmaf(s[mi][ns][1], cs, -12.0f));
        float p2 = __builtin_amdgcn_exp2f(fmaf(s[mi][ns][2], cs, -12.0f));
        float p3 = __builtin_amdgcn_exp2f(fmaf(s[mi][ns][3], cs, -12.0f));
        lacc += (p0 + p1) + (p2 + p3);
        X[ns] = cvtpk(p0, p1);
        Y[ns] = cvtpk(p2, p3);
      }
      lrow[mi] += lacc;
#pragma unroll
      for (int ks = 0; ks < 2; ++ks) {
        u32 a0 = X[2 * ks], b0 = X[2 * ks + 1];
        u32 a1 = Y[2 * ks], b1 = Y[2 * ks + 1];
        p32swap(a0, b0); p16swap(a0, b0);
        p32swap(a1, b1); p16swap(a1, b1);
        union { u32 u[4]; short8 v; } t;
        t.u[0] = a0; t.u[1] = a1; t.u[2] = b0; t.u[3] = b1;
        pf[mi][ks] = t.v;
      }
    }

    for (int ks = 0; ks < 2; ++ks) {
      short8 vf[4];
      for (int ds = 0; ds < 4; ++ds) {
        int dv = ds * 16 + lq;
        vf[ds] = *(const short8*)(Vts + (size_t)dv * 64 +
                                  (((ks * 4 + qr) ^ (lq & 7)) << 3));
      }
      __builtin_amdgcn_s_setprio(1);
      for (int mi = 0; mi < 2; ++mi)
        for (int ds = 0; ds < 4; ++ds)
          o[mi][ds] = __builtin_amdgcn_mfma_f32_16x16x32_bf16(
              vf[ds], pf[mi][ks], o[mi][ds], 0, 0, 0);
      __builtin_amdgcn_s_setprio(0);
    }
  }

  for (int mi = 0; mi < 2; ++mi) {
    float l = lrow[mi];
    l += __shfl_xor(l, 16, 64);
    l += __shfl_xor(l, 32, 64);
    float linv = 1.f / fmaxf(l, 1e-30f);
    int row = qbase + mi * 16 + lq;
    u16* dst = ctx + (size_t)row * ldctx + h * 64 + qr * 4;
    for (int ds = 0; ds < 4; ++ds) {
      u32 lo = cvtpk(o[mi][ds][0] * linv, o[mi][ds][1] * linv);
      u32 hi = cvtpk(o[mi][ds][2] * linv, o[mi][ds][3] * linv);
      *(uint2*)(dst + ds * 16) = make_uint2(lo, hi);
    }
  }
}

extern "C" void kernel_launch(void* const* d_in, const int* in_sizes, int n_in,
                              void* d_out, int out_size, void* d_ws, size_t ws_size,
                              hipStream_t stream) {
  float* out = (float*)d_out;  // reference output dtype is fp32

  const void *px = nullptr, *pwq = nullptr, *pbq = nullptr, *pwo = nullptr, *pbo = nullptr;
  if (n_in == 5) {
    for (int i = 0; i < 5; ++i) {
      switch (in_sizes[i]) {
        case 4194304: px = d_in[i]; break;
        case 3145728: pwq = d_in[i]; break;
        case 3072:    pbq = d_in[i]; break;
        case 1048576: pwo = d_in[i]; break;
        case 1024:    pbo = d_in[i]; break;
        default: break;
      }
    }
  }
  if (!px || !pwq || !pbq || !pwo || !pbo) {
    px = d_in[0]; pwq = d_in[1]; pbq = d_in[2]; pwo = d_in[3]; pbo = d_in[4];
  }

  int* flag = (int*)d_ws;
  u16* qkv = (u16*)((char*)d_ws + 64);
  u16* ctx = qkv;  // aliases dead Q-region (row stride 3072); race-free per block

  const size_t nQKV = (size_t)4096 * 3072;
  const size_t nVt = (size_t)16 * 64 * 4096;
  const size_t nx = 4194304, nwq = 3145728, nwo = 1048576;
  u16* Vtg = qkv + nQKV;
  const size_t need_vt = 64 + (nQKV + nVt) * 2;
  const size_t need_full = need_vt + (nx + nwq + 4096 + nwo + 1024) * 2;

  if (ws_size >= need_full) {
    u16* xb    = Vtg + nVt;
    u16* wqkvb = xb + nx;
    u16* bqkvb = wqkvb + nwq;
    u16* wob   = bqkvb + 4096;
    u16* bob   = wob + nwo;
    convert_all<<<4098, 256, 0, stream>>>(px, pwq, pbq, pwo, pbo,
                                          xb, wqkvb, bqkvb, wob, bob);

    gemm_bt<<<dim3(24, 32), 256, 0, stream>>>(xb, wqkvb, bqkvb, qkv,
                                              4096, 3072, 1024, 1024, 1024, 3072,
                                              0, 0, 0, flag);
    transpose_v<<<dim3(64, 16), 256, 0, stream>>>(qkv, Vtg);
    attn_split<<<dim3(32, 16), 512, 0, stream>>>(qkv, Vtg, ctx, 3072);
    gemm_bt_ks<<<dim3(8, 32), 512, 0, stream>>>(ctx, wob, bob, out,
                                                1024, 3072, 1024, 1024);
  } else if (ws_size >= need_vt) {
    detect_dtype<<<1, 256, 0, stream>>>((const u16*)px, flag);
    gemm_bt<<<dim3(24, 32), 256, 0, stream>>>(px, pwq, pbq, qkv,
                                              4096, 3072, 1024, 1024, 1024, 3072,
                                              1, 1, 0, flag);
    transpose_v<<<dim3(64, 16), 256, 0, stream>>>(qkv, Vtg);
    attn_split<<<dim3(32, 16), 512, 0, stream>>>(qkv, Vtg, ctx, 3072);
    gemm_bt<<<dim3(8, 32), 256, 0, stream>>>(ctx, pwo, pbo, out,
                                             4096, 1024, 1024, 3072, 1024, 1024,
                                             0, 1, 1, flag);
  } else {
    detect_dtype<<<1, 256, 0, stream>>>((const u16*)px, flag);
    gemm_bt<<<dim3(24, 32), 256, 0, stream>>>(px, pwq, pbq, qkv,
                                              4096, 3072, 1024, 1024, 1024, 3072,
                                              1, 1, 0, flag);
    attn_fused<<<dim3(32, 16), 256, 0, stream>>>(qkv, (const u16*)nullptr, ctx, 3072);
    gemm_bt<<<dim3(8, 32), 256, 0, stream>>>(ctx, pwo, pbo, out,
                                             4096, 1024, 1024, 3072, 1024, 1024,
                                             0, 1, 1, flag);
  }
}

// Round 10
// 244.559 us; speedup vs baseline: 1.2947x; 1.0634x over previous
//
#include <hip/hip_runtime.h>

typedef unsigned short u16;
typedef unsigned int u32;
typedef __attribute__((ext_vector_type(8))) short short8;
typedef __attribute__((ext_vector_type(4))) float f32x4;

__device__ __forceinline__ u16 f2b(float f) {  // RNE
  union { float f; unsigned u; } v; v.f = f;
  unsigned r = (v.u + 0x7FFFu + ((v.u >> 16) & 1u)) >> 16;
  return (u16)r;
}
__device__ __forceinline__ float b2f(u16 b) {
  union { unsigned u; float f; } v; v.u = ((unsigned)b) << 16;
  return v.f;
}
// Single-instruction packed f32->bf16 (RNE). T12 recipe: no builtin on gfx950.
__device__ __forceinline__ u32 cvtpk(float a, float b) {
  u32 r;
  asm("v_cvt_pk_bf16_f32 %0, %1, %2" : "=v"(r) : "v"(a), "v"(b));
  return r;
}
// Cross-lane row swaps (gfx950). Both operands are read-write.
__device__ __forceinline__ void p32swap(u32& a, u32& b) {
  asm("v_permlane32_swap_b32 %0, %1" : "+v"(a), "+v"(b));
}
__device__ __forceinline__ void p16swap(u32& a, u32& b) {
  asm("v_permlane16_swap_b32 %0, %1" : "+v"(a), "+v"(b));
}
__device__ __forceinline__ float ldf(const void* p, size_t i, int f32) {
  return f32 ? ((const float*)p)[i] : b2f(((const u16*)p)[i]);
}

// fp32 vs bf16 input detector (HW-verified; fp32 on this harness).
// Kept for the reduced-workspace fallback paths.
__global__ __launch_bounds__(256) void detect_dtype(const u16* __restrict__ x,
                                                    int* __restrict__ flag) {
  __shared__ int cnt;
  if (threadIdx.x == 0) cnt = 0;
  __syncthreads();
  int local = 0;
  for (int p = threadIdx.x; p < 512; p += 256) {
    int e = (x[2 * p] >> 7) & 0xFF;
    if (e >= 0xC0) local++;
  }
  atomicAdd(&cnt, local);
  __syncthreads();
  if (threadIdx.x == 0) flag[0] = (cnt >= 16) ? 1 : 0;
}

// Fused one-time fp32->bf16 convert of all 5 tensors (1 launch, self-detecting).
__global__ __launch_bounds__(256) void convert_all(
    const void* __restrict__ px, const void* __restrict__ pwq,
    const void* __restrict__ pbq, const void* __restrict__ pwo,
    const void* __restrict__ pbo, u16* __restrict__ xb,
    u16* __restrict__ wqkvb, u16* __restrict__ bqkvb, u16* __restrict__ wob,
    u16* __restrict__ bob) {
  __shared__ int sf;
  if (threadIdx.x == 0) sf = 0;
  __syncthreads();
  {
    const u16* xr = (const u16*)px;
    int local = 0;
    for (int p = threadIdx.x; p < 512; p += 256) {
      int e = (xr[2 * p] >> 7) & 0xFF;
      if (e >= 0xC0) local++;
    }
    atomicAdd(&sf, local);
  }
  __syncthreads();
  const int isf32 = (sf >= 16);

  int i = blockIdx.x * 256 + threadIdx.x;
  const void* in; u16* out; size_t g;
  if (i < 524288)       { in = px;  out = xb;    g = (size_t)i; }
  else if (i < 917504)  { in = pwq; out = wqkvb; g = (size_t)(i - 524288); }
  else if (i < 917888)  { in = pbq; out = bqkvb; g = (size_t)(i - 917504); }
  else if (i < 1048960) { in = pwo; out = wob;   g = (size_t)(i - 917888); }
  else                  { in = pbo; out = bob;   g = (size_t)(i - 1048960); }
  size_t base = g * 8;
  if (isf32) {
    const float* p = (const float*)in + base;
    float4 v0 = *(const float4*)p, v1 = *(const float4*)(p + 4);
    union { short8 v; u16 e[8]; } t;
    t.e[0]=f2b(v0.x); t.e[1]=f2b(v0.y); t.e[2]=f2b(v0.z); t.e[3]=f2b(v0.w);
    t.e[4]=f2b(v1.x); t.e[5]=f2b(v1.y); t.e[6]=f2b(v1.z); t.e[7]=f2b(v1.w);
    *(short8*)(out + base) = t.v;
  } else {
    *(short8*)(out + base) = *(const short8*)((const u16*)in + base);
  }
}

// qkv[n][3072] V-cols -> Vtg[h][64][4096]  (HW-verified)
__global__ __launch_bounds__(256) void transpose_v(const u16* __restrict__ qkv,
                                                   u16* __restrict__ Vt) {
  __shared__ u16 T[64 * 72];
  const int tid = threadIdx.x;
  const int h = blockIdx.y;
  const int s0 = blockIdx.x * 64;
  for (int r = 0; r < 2; ++r) {
    int cid = r * 256 + tid;
    int s = cid >> 3, c8 = cid & 7;
    union { short8 v; u16 u[8]; } uu;
    uu.v = *(const short8*)(qkv + (size_t)(s0 + s) * 3072 + 2048 + h * 64 + c8 * 8);
    for (int i = 0; i < 8; ++i) T[(c8 * 8 + i) * 72 + s] = uu.u[i];
  }
  __syncthreads();
  for (int r = 0; r < 2; ++r) {
    int cid = r * 256 + tid;
    int dd = cid >> 3, c8 = cid & 7;
    union { short8 v; u16 u[8]; } uu;
    for (int i = 0; i < 8; ++i) uu.u[i] = T[dd * 72 + c8 * 8 + i];
    *(short8*)(Vt + (size_t)(h * 64 + dd) * 4096 + s0 + c8 * 8) = uu.v;
  }
}

// gemm1 double-buffered (r10): bf16-only A[M][K]*B[N][K]^T + bias -> bf16 C.
// Same tile/compute/epilogue as verified gemm_bt; staging is PREFETCHED one
// K-tile ahead into the other LDS buffer, ONE barrier per iter (its implicit
// vmcnt(0) drains next-tile loads after a full iteration of compute — the
// r7 attn pattern, which measured 107.6->90.1 there). Old gemm_bt drained
// the current tile's loads immediately (exposed ~900cy HBM latency per iter).
__global__ __launch_bounds__(256) void gemm1_db(const u16* __restrict__ A,
                                                const u16* __restrict__ B,
                                                const u16* __restrict__ bias,
                                                u16* __restrict__ C,
                                                int K, int lda, int ldb, int ldc) {
  __shared__ __align__(16) u16 sm[2][16384];  // per buf: A(8192 u16)|B(8192 u16)
  const int tid = threadIdx.x;
  const int w = tid >> 6, lane = tid & 63;
  const int lq = lane & 15, qr = lane >> 4;
  const int m0 = blockIdx.y * 128, n0 = blockIdx.x * 128;
  const int wm = (w >> 1) * 64, wn = (w & 1) * 64;

  f32x4 acc[4][4];
  for (int i = 0; i < 4; i++)
    for (int j = 0; j < 4; j++) acc[i][j] = (f32x4){0.f, 0.f, 0.f, 0.f};
  float bv[4];
  for (int ns = 0; ns < 4; ++ns) bv[ns] = b2f(bias[n0 + wn + ns * 16 + lq]);

  const int rs = tid >> 3, cs = tid & 7;
  const u16* gA = A + (size_t)(m0 + rs) * lda + cs * 8;
  const u16* gB = B + (size_t)(n0 + rs) * ldb + cs * 8;
  const int lofs = (tid & ~63) << 3;  // wave-uniform; HW adds lane*16B

#define GSTAGE(buf, k0)                                                      \
  do {                                                                       \
    u16* As_ = &sm[buf][0];                                                  \
    u16* Bs_ = &sm[buf][8192];                                               \
    for (int r = 0; r < 4; ++r) {                                            \
      __builtin_amdgcn_global_load_lds(gA + (size_t)(r * 32) * lda + (k0),   \
                                       As_ + lofs + r * 2048, 16, 0, 0);     \
      __builtin_amdgcn_global_load_lds(gB + (size_t)(r * 32) * ldb + (k0),   \
                                       Bs_ + lofs + r * 2048, 16, 0, 0);     \
    }                                                                        \
  } while (0)

  GSTAGE(0, 0);
  __syncthreads();  // drain prologue loads

  const int nk = K >> 6;
  for (int kt = 0; kt < nk; ++kt) {
    const int cur = kt & 1;
    if (kt + 1 < nk) GSTAGE(cur ^ 1, (kt + 1) * 64);  // prefetch next tile
    const u16* As = &sm[cur][0];
    const u16* Bs = &sm[cur][8192];
    for (int ks = 0; ks < 2; ++ks) {
      short8 af[4], bf[4];
      const int sw = ks * 4 + qr;
      for (int i = 0; i < 4; i++) {
        af[i] = *(const short8*)(As + (wm + i * 16 + lq) * 64 + sw * 8);
        bf[i] = *(const short8*)(Bs + (wn + i * 16 + lq) * 64 + sw * 8);
      }
      for (int mi = 0; mi < 4; mi++)
        for (int ni = 0; ni < 4; ni++)
          acc[mi][ni] = __builtin_amdgcn_mfma_f32_16x16x32_bf16(
              af[mi], bf[ni], acc[mi][ni], 0, 0, 0);
    }
    __syncthreads();  // reads-done for buf[cur] + drains next-tile loads
  }
#undef GSTAGE

  // bf16 epilogue (verified layout, stride 132) into the flat 64KB LDS
  u16* SH = &sm[0][0];
  for (int mi = 0; mi < 4; mi++)
    for (int ni = 0; ni < 4; ni++)
      for (int r = 0; r < 4; ++r)
        SH[(wm + mi * 16 + qr * 4 + r) * 132 + wn + ni * 16 + lq] =
            f2b(acc[mi][ni][r] + bv[ni]);
  __syncthreads();
  for (int it = 0; it < 8; ++it) {
    int idx = it * 256 + tid;
    int row = idx >> 4, c8 = idx & 15;
    *(short8*)(C + (size_t)(m0 + row) * ldc + n0 + c8 * 8) =
        *(const short8*)(SH + row * 132 + c8 * 8);
  }
}

// C[M][N] = A[M][K]*B[N][K]^T + bias[N]; r2-verified core; r8 direct fp32
// epilogue. Used for the fallback paths.
__global__ __launch_bounds__(256) void gemm_bt(const void* __restrict__ A,
                                               const void* __restrict__ B,
                                               const void* __restrict__ bias,
                                               void* __restrict__ C,
                                               int M, int N, int K,
                                               int lda, int ldb, int ldc,
                                               int aMay, int bMay, int outF32,
                                               const int* __restrict__ flag) {
  __shared__ __align__(16) u16 sm[128 * 132];  // 33792 B; reused by epilogue
  u16* As = sm;
  u16* Bs = sm + 128 * 64;
  const int f = flag[0];
  const int a32 = aMay && f, b32 = bMay && f;
  const int tid = threadIdx.x;
  const int w = tid >> 6, lane = tid & 63;
  const int lq = lane & 15, qr = lane >> 4;
  const int m0 = blockIdx.y * 128, n0 = blockIdx.x * 128;
  const int wm = (w >> 1) * 64, wn = (w & 1) * 64;

  f32x4 acc[4][4];
  for (int i = 0; i < 4; i++)
    for (int j = 0; j < 4; j++) acc[i][j] = (f32x4){0.f, 0.f, 0.f, 0.f};
  float bv[4];
  for (int ns = 0; ns < 4; ++ns) bv[ns] = ldf(bias, n0 + wn + ns * 16 + lq, b32);

  // hoisted staging addresses (bf16 fast path)
  const int rs = tid >> 3, cs = tid & 7;
  const u16* gA = (const u16*)A + (size_t)(m0 + rs) * lda + cs * 8;
  const u16* gB = (const u16*)B + (size_t)(n0 + rs) * ldb + cs * 8;
  u16* lA = As + ((tid & ~63) << 3);  // wave-uniform base; HW adds lane*16B
  u16* lB = Bs + ((tid & ~63) << 3);

  for (int k0 = 0; k0 < K; k0 += 64) {
    if (!(a32 | b32)) {
      for (int r = 0; r < 4; ++r) {
        __builtin_amdgcn_global_load_lds(gA + (size_t)(r * 32) * lda + k0,
                                         lA + r * 2048, 16, 0, 0);
        __builtin_amdgcn_global_load_lds(gB + (size_t)(r * 32) * ldb + k0,
                                         lB + r * 2048, 16, 0, 0);
      }
    } else {
      for (int r = 0; r < 4; ++r) {
        int cid = r * 256 + tid;
        int row = cid >> 3, c = cid & 7;
        if (a32) {
          const float* p = (const float*)A + (size_t)(m0 + row) * lda + k0 + c * 8;
          float4 v0 = *(const float4*)p, v1 = *(const float4*)(p + 4);
          union { short8 v; u16 e[8]; } t;
          t.e[0]=f2b(v0.x); t.e[1]=f2b(v0.y); t.e[2]=f2b(v0.z); t.e[3]=f2b(v0.w);
          t.e[4]=f2b(v1.x); t.e[5]=f2b(v1.y); t.e[6]=f2b(v1.z); t.e[7]=f2b(v1.w);
          *(short8*)(As + row * 64 + c * 8) = t.v;
        } else {
          *(short8*)(As + row * 64 + c * 8) =
              *(const short8*)((const u16*)A + (size_t)(m0 + row) * lda + k0 + c * 8);
        }
        if (b32) {
          const float* p = (const float*)B + (size_t)(n0 + row) * ldb + k0 + c * 8;
          float4 v0 = *(const float4*)p, v1 = *(const float4*)(p + 4);
          union { short8 v; u16 e[8]; } t;
          t.e[0]=f2b(v0.x); t.e[1]=f2b(v0.y); t.e[2]=f2b(v0.z); t.e[3]=f2b(v0.w);
          t.e[4]=f2b(v1.x); t.e[5]=f2b(v1.y); t.e[6]=f2b(v1.z); t.e[7]=f2b(v1.w);
          *(short8*)(Bs + row * 64 + c * 8) = t.v;
        } else {
          *(short8*)(Bs + row * 64 + c * 8) =
              *(const short8*)((const u16*)B + (size_t)(n0 + row) * ldb + k0 + c * 8);
        }
      }
    }
    __syncthreads();
    for (int ks = 0; ks < 2; ++ks) {
      short8 af[4], bf[4];
      const int sw = ks * 4 + qr;
      for (int i = 0; i < 4; i++) {
        af[i] = *(const short8*)(As + (wm + i * 16 + lq) * 64 + sw * 8);
        bf[i] = *(const short8*)(Bs + (wn + i * 16 + lq) * 64 + sw * 8);
      }
      for (int mi = 0; mi < 4; mi++)
        for (int ni = 0; ni < 4; ni++)
          acc[mi][ni] = __builtin_amdgcn_mfma_f32_16x16x32_bf16(
              af[mi], bf[ni], acc[mi][ni], 0, 0, 0);
    }
    __syncthreads();
  }

  if (!outF32) {
    u16* SH = sm;
    for (int mi = 0; mi < 4; mi++)
      for (int ni = 0; ni < 4; ni++)
        for (int r = 0; r < 4; ++r)
          SH[(wm + mi * 16 + qr * 4 + r) * 132 + wn + ni * 16 + lq] =
              f2b(acc[mi][ni][r] + bv[ni]);
    __syncthreads();
    for (int it = 0; it < 8; ++it) {
      int idx = it * 256 + tid;
      int row = idx >> 4, c8 = idx & 15;
      *(short8*)((u16*)C + (size_t)(m0 + row) * ldc + n0 + c8 * 8) =
          *(const short8*)(SH + row * 132 + c8 * 8);
    }
  } else {
    // direct fp32 stores (r8): no LDS roundtrip, no barriers
    float* Cf = (float*)C;
    for (int mi = 0; mi < 4; mi++) {
      int row = m0 + wm + mi * 16 + qr * 4;
      for (int r = 0; r < 4; ++r) {
        float* rp = Cf + (size_t)(row + r) * ldc + n0 + wn;
        for (int ni = 0; ni < 4; ni++)
          rp[ni * 16 + lq] = acc[mi][ni][r] + bv[ni];
      }
    }
  }
}

// gemm2 K-split kernel (r9; measured ~= plain gemm_bt, kept).
__global__ __launch_bounds__(512, 2) void gemm_bt_ks(const u16* __restrict__ A,
                                                     const u16* __restrict__ B,
                                                     const u16* __restrict__ bias,
                                                     float* __restrict__ C,
                                                     int K, int lda, int ldb, int ldc) {
  __shared__ __align__(16) u16 sm[2][16384];  // per-half: A tile | B tile
  const int tid = threadIdx.x;
  const int w = tid >> 6, lane = tid & 63;
  const int half = w >> 2, wq = w & 3;
  const int ht = tid & 255;
  const int lq = lane & 15, qr = lane >> 4;
  const int m0 = blockIdx.y * 128, n0 = blockIdx.x * 128;
  const int wm = (wq >> 1) * 64, wn = (wq & 1) * 64;
  const int kh = K >> 1;

  u16* As = &sm[half][0];
  u16* Bs = &sm[half][8192];

  f32x4 acc[4][4];
  for (int i = 0; i < 4; i++)
    for (int j = 0; j < 4; j++) acc[i][j] = (f32x4){0.f, 0.f, 0.f, 0.f};
  float bv[4];
  for (int ns = 0; ns < 4; ++ns) bv[ns] = b2f(bias[n0 + wn + ns * 16 + lq]);

  const int rs = ht >> 3, cs = ht & 7;
  const u16* gA = A + (size_t)(m0 + rs) * lda + half * kh + cs * 8;
  const u16* gB = B + (size_t)(n0 + rs) * ldb + half * kh + cs * 8;
  u16* lA = As + ((ht & ~63) << 3);  // wave-uniform base; HW adds lane*16B
  u16* lB = Bs + ((ht & ~63) << 3);

  for (int k0 = 0; k0 < kh; k0 += 64) {
    for (int r = 0; r < 4; ++r) {
      __builtin_amdgcn_global_load_lds(gA + (size_t)(r * 32) * lda + k0,
                                       lA + r * 2048, 16, 0, 0);
      __builtin_amdgcn_global_load_lds(gB + (size_t)(r * 32) * ldb + k0,
                                       lB + r * 2048, 16, 0, 0);
    }
    __syncthreads();
    for (int ks = 0; ks < 2; ++ks) {
      short8 af[4], bf[4];
      const int sw = ks * 4 + qr;
      for (int i = 0; i < 4; i++) {
        af[i] = *(const short8*)(As + (wm + i * 16 + lq) * 64 + sw * 8);
        bf[i] = *(const short8*)(Bs + (wn + i * 16 + lq) * 64 + sw * 8);
      }
      for (int mi = 0; mi < 4; mi++)
        for (int ni = 0; ni < 4; ni++)
          acc[mi][ni] = __builtin_amdgcn_mfma_f32_16x16x32_bf16(
              af[mi], bf[ni], acc[mi][ni], 0, 0, 0);
    }
    __syncthreads();
  }

  // cross-half combine: 2 rounds x 2 mi (32 floats/thread, stride-33 regions)
  float* CB = (float*)&sm[0][0];
  float* p = CB + (size_t)ht * 33;
  for (int t = 0; t < 2; ++t) {
    if (half == 1) {
      for (int u = 0; u < 2; ++u)
        for (int ni = 0; ni < 4; ++ni)
          for (int r = 0; r < 4; ++r)
            p[u * 16 + ni * 4 + r] = acc[2 * t + u][ni][r];
    }
    __syncthreads();
    if (half == 0) {
      for (int u = 0; u < 2; ++u)
        for (int ni = 0; ni < 4; ++ni)
          for (int r = 0; r < 4; ++r)
            acc[2 * t + u][ni][r] += p[u * 16 + ni * 4 + r];
    }
    __syncthreads();
  }

  if (half == 0) {
    for (int mi = 0; mi < 4; mi++) {
      int row = m0 + wm + mi * 16 + qr * 4;
      for (int r = 0; r < 4; ++r) {
        float* rp = C + (size_t)(row + r) * ldc + n0 + wn;
        for (int ni = 0; ni < 4; ni++)
          rp[ni * 16 + lq] = acc[mi][ni][r] + bv[ni];
      }
    }
  }
}

// Flash attention (r7-verified, 90.1 µs): KV-split + glds staging + dbuf +
// one barrier/iter; r7 combine epilogue (two stride-17 rounds).
__global__ __launch_bounds__(512, 2) void attn_split(const u16* __restrict__ qkv,
                                                     const u16* __restrict__ Vtg,
                                                     u16* __restrict__ ctx, int ldctx) {
  __shared__ __align__(16) u16 SMEM[2][16384];
  const int tid = threadIdx.x;
  const int w = tid >> 6, lane = tid & 63;
  const int half = w >> 2, wq = w & 3, wl = w & 3;
  const int lq = lane & 15, qr = lane >> 4;
  const int qb = blockIdx.x, h = blockIdx.y;
  const int qbase = qb * 128 + wq * 32;
  const float cs = 0.18033688011112042f;  // log2(e)/8

  short8 qf[2][2];
#pragma unroll
  for (int mi = 0; mi < 2; ++mi)
#pragma unroll
    for (int ks = 0; ks < 2; ++ks)
      qf[mi][ks] = *(const short8*)(qkv + (size_t)(qbase + mi * 16 + lq) * 3072 +
                                    h * 64 + ks * 32 + qr * 8);

  f32x4 o[2][4];
#pragma unroll
  for (int mi = 0; mi < 2; ++mi)
#pragma unroll
    for (int ds = 0; ds < 4; ++ds) o[mi][ds] = (f32x4){0.f, 0.f, 0.f, 0.f};
  float lrow[2] = {0.f, 0.f};

  // staging: per-lane pre-swizzled global sources; wave-uniform LDS bases.
  const int csw = ((lane & 7) ^ (lane >> 3)) << 3;
  const int r0v = wl * 8 + (lane >> 3);  // row covered by this lane
  const u16* sK0 = qkv + (size_t)(half * 2048 + r0v) * 3072 + 1024 + h * 64 + csw;
  const u16* sK1 = sK0 + (size_t)32 * 3072;
  const u16* sV0 = Vtg + (size_t)(h * 64 + r0v) * 4096 + half * 2048 + csw;
  const u16* sV1 = sV0 + (size_t)32 * 4096;
  const int kb = half * 4096 + wl * 512;         // u16 offset, wave-uniform
  const int vb = 8192 + half * 4096 + wl * 512;

#define STAGE(buf)                                                          \
  do {                                                                      \
    u16* B_ = &SMEM[buf][0];                                                \
    __builtin_amdgcn_global_load_lds(sK0, B_ + kb, 16, 0, 0);               \
    __builtin_amdgcn_global_load_lds(sK1, B_ + kb + 2048, 16, 0, 0);        \
    __builtin_amdgcn_global_load_lds(sV0, B_ + vb, 16, 0, 0);               \
    __builtin_amdgcn_global_load_lds(sV1, B_ + vb + 2048, 16, 0, 0);        \
    sK0 += (size_t)64 * 3072; sK1 += (size_t)64 * 3072;                     \
    sV0 += 64; sV1 += 64;                                                   \
  } while (0)

  STAGE(0);
  __syncthreads();  // drain prologue loads + sync

  for (int it = 0; it < 32; ++it) {
    const int cur = it & 1;
    if (it + 1 < 32) STAGE(cur ^ 1);  // next tile; drains at loop-end barrier
    const u16* Kh = &SMEM[cur][half * 4096];
    const u16* Vh = &SMEM[cur][8192 + half * 4096];

    // QK^T (swapped: K is A-operand, Q is B-operand)
    f32x4 s[2][4];
#pragma unroll
    for (int mi = 0; mi < 2; ++mi)
#pragma unroll
      for (int ns = 0; ns < 4; ++ns) s[mi][ns] = (f32x4){0.f, 0.f, 0.f, 0.f};
#pragma unroll
    for (int ks = 0; ks < 2; ++ks) {
      short8 kf[4];
#pragma unroll
      for (int ns = 0; ns < 4; ++ns) {
        int rk = ns * 16 + lq;
        kf[ns] = *(const short8*)(Kh + rk * 64 + (((ks * 4 + qr) ^ (lq & 7)) << 3));
      }
      __builtin_amdgcn_s_setprio(1);
#pragma unroll
      for (int mi = 0; mi < 2; ++mi)
#pragma unroll
        for (int ns = 0; ns < 4; ++ns)
          s[mi][ns] = __builtin_amdgcn_mfma_f32_16x16x32_bf16(
              kf[ns], qf[mi][ks], s[mi][ns], 0, 0, 0);
      __builtin_amdgcn_s_setprio(0);
    }

    // fixed-max softmax + in-register P exchange (T12)
    short8 pf[2][2];
#pragma unroll
    for (int mi = 0; mi < 2; ++mi) {
      float lacc = 0.f;
      u32 X[4], Y[4];
#pragma unroll
      for (int ns = 0; ns < 4; ++ns) {
        float p0 = __builtin_amdgcn_exp2f(fmaf(s[mi][ns][0], cs, -12.0f));
        float p1 = __builtin_amdgcn_exp2f(fmaf(s[mi][ns][1], cs, -12.0f));
        float p2 = __builtin_amdgcn_exp2f(fmaf(s[mi][ns][2], cs, -12.0f));
        float p3 = __builtin_amdgcn_exp2f(fmaf(s[mi][ns][3], cs, -12.0f));
        lacc += (p0 + p1) + (p2 + p3);
        X[ns] = cvtpk(p0, p1);
        Y[ns] = cvtpk(p2, p3);
      }
      lrow[mi] += lacc;
#pragma unroll
      for (int ks = 0; ks < 2; ++ks) {
        u32 a0 = X[2 * ks], b0 = X[2 * ks + 1];
        u32 a1 = Y[2 * ks], b1 = Y[2 * ks + 1];
        p32swap(a0, b0); p16swap(a0, b0);
        p32swap(a1, b1); p16swap(a1, b1);
        union { u32 u[4]; short8 v; } t;
        t.u[0] = a0; t.u[1] = a1; t.u[2] = b0; t.u[3] = b1;
        pf[mi][ks] = t.v;
      }
    }

    // PV (swapped: V is A-operand, P is B-operand)
#pragma unroll
    for (int ks = 0; ks < 2; ++ks) {
      short8 vf[4];
#pragma unroll
      for (int ds = 0; ds < 4; ++ds) {
        int dv = ds * 16 + lq;
        vf[ds] = *(const short8*)(Vh + (size_t)dv * 64 +
                                  (((ks * 4 + qr) ^ (lq & 7)) << 3));
      }
      __builtin_amdgcn_s_setprio(1);
#pragma unroll
      for (int mi = 0; mi < 2; ++mi)
#pragma unroll
        for (int ds = 0; ds < 4; ++ds)
          o[mi][ds] = __builtin_amdgcn_mfma_f32_16x16x32_bf16(
              vf[ds], pf[mi][ks], o[mi][ds], 0, 0, 0);
      __builtin_amdgcn_s_setprio(0);
    }
    __syncthreads();  // compute-done + vmcnt(0) drain of next-tile loads
  }
#undef STAGE

  // in-block combine (r7-verified): per-mi rounds, stride-17 fp32 regions.
  float* CB = (float*)&SMEM[0][0];
#pragma unroll
  for (int mi = 0; mi < 2; ++mi) {
    float* p = CB + (size_t)(wq * 64 + lane) * 17;
    if (half == 1) {
#pragma unroll
      for (int ds = 0; ds < 4; ++ds) {
        p[ds * 4 + 0] = o[mi][ds][0];
        p[ds * 4 + 1] = o[mi][ds][1];
        p[ds * 4 + 2] = o[mi][ds][2];
        p[ds * 4 + 3] = o[mi][ds][3];
      }
      p[16] = lrow[mi];
    }
    __syncthreads();
    if (half == 0) {
#pragma unroll
      for (int ds = 0; ds < 4; ++ds) {
        o[mi][ds][0] += p[ds * 4 + 0];
        o[mi][ds][1] += p[ds * 4 + 1];
        o[mi][ds][2] += p[ds * 4 + 2];
        o[mi][ds][3] += p[ds * 4 + 3];
      }
      lrow[mi] += p[16];
    }
    __syncthreads();
  }

  if (half == 0) {
#pragma unroll
    for (int mi = 0; mi < 2; ++mi) {
      float l = lrow[mi];
      l += __shfl_xor(l, 16, 64);
      l += __shfl_xor(l, 32, 64);
      float linv = 1.f / fmaxf(l, 1e-30f);
      int row = qbase + mi * 16 + lq;
      u16* dst = ctx + (size_t)row * ldctx + h * 64 + qr * 4;
#pragma unroll
      for (int ds = 0; ds < 4; ++ds) {
        u32 lo = cvtpk(o[mi][ds][0] * linv, o[mi][ds][1] * linv);
        u32 hi = cvtpk(o[mi][ds][2] * linv, o[mi][ds][3] * linv);
        *(uint2*)(dst + ds * 16) = make_uint2(lo, hi);
      }
    }
  }
}

// Legacy v7 kernel (256 threads) kept ONLY for the no-workspace fallback.
__global__ __launch_bounds__(256) void attn_fused(const u16* __restrict__ qkv,
                                                  const u16* __restrict__ Vtg,
                                                  u16* __restrict__ ctx, int ldctx) {
  __shared__ u16 Ks[64 * 64];
  __shared__ u16 Vts[64 * 64];
  const int tid = threadIdx.x;
  const int w = tid >> 6, lane = tid & 63;
  const int lq = lane & 15, qr = lane >> 4;
  const int qb = blockIdx.x, h = blockIdx.y;
  const int qbase = qb * 128 + w * 32;
  const float cs = 0.18033688011112042f;

  short8 qf[2][2];
  for (int mi = 0; mi < 2; ++mi)
    for (int ks = 0; ks < 2; ++ks)
      qf[mi][ks] = *(const short8*)(qkv + (size_t)(qbase + mi * 16 + lq) * 3072 +
                                    h * 64 + ks * 32 + qr * 8);

  f32x4 o[2][4];
  for (int mi = 0; mi < 2; ++mi)
    for (int ds = 0; ds < 4; ++ds) o[mi][ds] = (f32x4){0.f, 0.f, 0.f, 0.f};
  float lrow[2] = {0.f, 0.f};

  const int c = tid & 7, r0 = tid >> 3;
  u16* dKA = Ks + r0 * 64 + ((c ^ (r0 & 7)) << 3);
  u16* dKB = dKA + 32 * 64;
  const u16* sKA = qkv + (size_t)r0 * 3072 + 1024 + h * 64 + c * 8;
  const u16* sKB = sKA + (size_t)32 * 3072;
  const u16* sVfA = qkv + (size_t)r0 * 3072 + 2048 + h * 64 + c * 8;
  const u16* sVfB = sVfA + (size_t)32 * 3072;

  short8 rKA, rKB;
  union { short8 v; u16 e[8]; } ufA, ufB;
  rKA = *(const short8*)sKA; sKA += (size_t)64 * 3072;
  rKB = *(const short8*)sKB; sKB += (size_t)64 * 3072;
  ufA.v = *(const short8*)sVfA; sVfA += (size_t)64 * 3072;
  ufB.v = *(const short8*)sVfB; sVfB += (size_t)64 * 3072;

  for (int j0 = 0; j0 < 4096; j0 += 64) {
    __syncthreads();
    *(short8*)dKA = rKA;
    *(short8*)dKB = rKB;
    {
      const int jc = r0 >> 3;
      for (int i = 0; i < 8; ++i)
        Vts[(c * 8 + i) * 64 + ((jc ^ i) << 3) + (r0 & 7)] = ufA.e[i];
    }
    {
      const int jc = (r0 + 32) >> 3;
      for (int i = 0; i < 8; ++i)
        Vts[(c * 8 + i) * 64 + ((jc ^ i) << 3) + (r0 & 7)] = ufB.e[i];
    }
    __syncthreads();

    if (j0 + 64 < 4096) {
      rKA = *(const short8*)sKA; sKA += (size_t)64 * 3072;
      rKB = *(const short8*)sKB; sKB += (size_t)64 * 3072;
      ufA.v = *(const short8*)sVfA; sVfA += (size_t)64 * 3072;
      ufB.v = *(const short8*)sVfB; sVfB += (size_t)64 * 3072;
    }

    f32x4 s[2][4];
    for (int mi = 0; mi < 2; ++mi)
      for (int ns = 0; ns < 4; ++ns) s[mi][ns] = (f32x4){0.f, 0.f, 0.f, 0.f};
    for (int ks = 0; ks < 2; ++ks) {
      short8 kf[4];
      for (int ns = 0; ns < 4; ++ns) {
        int rk = ns * 16 + lq;
        kf[ns] = *(const short8*)(Ks + rk * 64 + (((ks * 4 + qr) ^ (lq & 7)) << 3));
      }
      __builtin_amdgcn_s_setprio(1);
      for (int mi = 0; mi < 2; ++mi)
        for (int ns = 0; ns < 4; ++ns)
          s[mi][ns] = __builtin_amdgcn_mfma_f32_16x16x32_bf16(
              kf[ns], qf[mi][ks], s[mi][ns], 0, 0, 0);
      __builtin_amdgcn_s_setprio(0);
    }

    short8 pf[2][2];
#pragma unroll
    for (int mi = 0; mi < 2; ++mi) {
      float lacc = 0.f;
      u32 X[4], Y[4];
#pragma unroll
      for (int ns = 0; ns < 4; ++ns) {
        float p0 = __builtin_amdgcn_exp2f(fmaf(s[mi][ns][0], cs, -12.0f));
        float p1 = __builtin_amdgcn_exp2f(fmaf(s[mi][ns][1], cs, -12.0f));
        float p2 = __builtin_amdgcn_exp2f(fmaf(s[mi][ns][2], cs, -12.0f));
        float p3 = __builtin_amdgcn_exp2f(fmaf(s[mi][ns][3], cs, -12.0f));
        lacc += (p0 + p1) + (p2 + p3);
        X[ns] = cvtpk(p0, p1);
        Y[ns] = cvtpk(p2, p3);
      }
      lrow[mi] += lacc;
#pragma unroll
      for (int ks = 0; ks < 2; ++ks) {
        u32 a0 = X[2 * ks], b0 = X[2 * ks + 1];
        u32 a1 = Y[2 * ks], b1 = Y[2 * ks + 1];
        p32swap(a0, b0); p16swap(a0, b0);
        p32swap(a1, b1); p16swap(a1, b1);
        union { u32 u[4]; short8 v; } t;
        t.u[0] = a0; t.u[1] = a1; t.u[2] = b0; t.u[3] = b1;
        pf[mi][ks] = t.v;
      }
    }

    for (int ks = 0; ks < 2; ++ks) {
      short8 vf[4];
      for (int ds = 0; ds < 4; ++ds) {
        int dv = ds * 16 + lq;
        vf[ds] = *(const short8*)(Vts + (size_t)dv * 64 +
                                  (((ks * 4 + qr) ^ (lq & 7)) << 3));
      }
      __builtin_amdgcn_s_setprio(1);
      for (int mi = 0; mi < 2; ++mi)
        for (int ds = 0; ds < 4; ++ds)
          o[mi][ds] = __builtin_amdgcn_mfma_f32_16x16x32_bf16(
              vf[ds], pf[mi][ks], o[mi][ds], 0, 0, 0);
      __builtin_amdgcn_s_setprio(0);
    }
  }

  for (int mi = 0; mi < 2; ++mi) {
    float l = lrow[mi];
    l += __shfl_xor(l, 16, 64);
    l += __shfl_xor(l, 32, 64);
    float linv = 1.f / fmaxf(l, 1e-30f);
    int row = qbase + mi * 16 + lq;
    u16* dst = ctx + (size_t)row * ldctx + h * 64 + qr * 4;
    for (int ds = 0; ds < 4; ++ds) {
      u32 lo = cvtpk(o[mi][ds][0] * linv, o[mi][ds][1] * linv);
      u32 hi = cvtpk(o[mi][ds][2] * linv, o[mi][ds][3] * linv);
      *(uint2*)(dst + ds * 16) = make_uint2(lo, hi);
    }
  }
}

extern "C" void kernel_launch(void* const* d_in, const int* in_sizes, int n_in,
                              void* d_out, int out_size, void* d_ws, size_t ws_size,
                              hipStream_t stream) {
  float* out = (float*)d_out;  // reference output dtype is fp32

  const void *px = nullptr, *pwq = nullptr, *pbq = nullptr, *pwo = nullptr, *pbo = nullptr;
  if (n_in == 5) {
    for (int i = 0; i < 5; ++i) {
      switch (in_sizes[i]) {
        case 4194304: px = d_in[i]; break;
        case 3145728: pwq = d_in[i]; break;
        case 3072:    pbq = d_in[i]; break;
        case 1048576: pwo = d_in[i]; break;
        case 1024:    pbo = d_in[i]; break;
        default: break;
      }
    }
  }
  if (!px || !pwq || !pbq || !pwo || !pbo) {
    px = d_in[0]; pwq = d_in[1]; pbq = d_in[2]; pwo = d_in[3]; pbo = d_in[4];
  }

  int* flag = (int*)d_ws;
  u16* qkv = (u16*)((char*)d_ws + 64);
  u16* ctx = qkv;  // aliases dead Q-region (row stride 3072); race-free per block

  const size_t nQKV = (size_t)4096 * 3072;
  const size_t nVt = (size_t)16 * 64 * 4096;
  const size_t nx = 4194304, nwq = 3145728, nwo = 1048576;
  u16* Vtg = qkv + nQKV;
  const size_t need_vt = 64 + (nQKV + nVt) * 2;
  const size_t need_full = need_vt + (nx + nwq + 4096 + nwo + 1024) * 2;

  if (ws_size >= need_full) {
    u16* xb    = Vtg + nVt;
    u16* wqkvb = xb + nx;
    u16* bqkvb = wqkvb + nwq;
    u16* wob   = bqkvb + 4096;
    u16* bob   = wob + nwo;
    convert_all<<<4098, 256, 0, stream>>>(px, pwq, pbq, pwo, pbo,
                                          xb, wqkvb, bqkvb, wob, bob);

    gemm1_db<<<dim3(24, 32), 256, 0, stream>>>(xb, wqkvb, bqkvb, qkv,
                                               1024, 1024, 1024, 3072);
    transpose_v<<<dim3(64, 16), 256, 0, stream>>>(qkv, Vtg);
    attn_split<<<dim3(32, 16), 512, 0, stream>>>(qkv, Vtg, ctx, 3072);
    gemm_bt_ks<<<dim3(8, 32), 512, 0, stream>>>(ctx, wob, bob, out,
                                                1024, 3072, 1024, 1024);
  } else if (ws_size >= need_vt) {
    detect_dtype<<<1, 256, 0, stream>>>((const u16*)px, flag);
    gemm_bt<<<dim3(24, 32), 256, 0, stream>>>(px, pwq, pbq, qkv,
                                              4096, 3072, 1024, 1024, 1024, 3072,
                                              1, 1, 0, flag);
    transpose_v<<<dim3(64, 16), 256, 0, stream>>>(qkv, Vtg);
    attn_split<<<dim3(32, 16), 512, 0, stream>>>(qkv, Vtg, ctx, 3072);
    gemm_bt<<<dim3(8, 32), 256, 0, stream>>>(ctx, pwo, pbo, out,
                                             4096, 1024, 1024, 3072, 1024, 1024,
                                             0, 1, 1, flag);
  } else {
    detect_dtype<<<1, 256, 0, stream>>>((const u16*)px, flag);
    gemm_bt<<<dim3(24, 32), 256, 0, stream>>>(px, pwq, pbq, qkv,
                                              4096, 3072, 1024, 1024, 1024, 3072,
                                              1, 1, 0, flag);
    attn_fused<<<dim3(32, 16), 256, 0, stream>>>(qkv, (const u16*)nullptr, ctx, 3072);
    gemm_bt<<<dim3(8, 32), 256, 0, stream>>>(ctx, pwo, pbo, out,
                                             4096, 1024, 1024, 3072, 1024, 1024,
                                             0, 1, 1, flag);
  }
}

// Round 11
// 235.525 us; speedup vs baseline: 1.3444x; 1.0384x over previous
//
#include <hip/hip_runtime.h>

typedef unsigned short u16;
typedef unsigned int u32;
typedef __attribute__((ext_vector_type(8))) short short8;
typedef __attribute__((ext_vector_type(4))) float f32x4;

__device__ __forceinline__ u16 f2b(float f) {  // RNE
  union { float f; unsigned u; } v; v.f = f;
  unsigned r = (v.u + 0x7FFFu + ((v.u >> 16) & 1u)) >> 16;
  return (u16)r;
}
__device__ __forceinline__ float b2f(u16 b) {
  union { unsigned u; float f; } v; v.u = ((unsigned)b) << 16;
  return v.f;
}
// Single-instruction packed f32->bf16 (RNE). T12 recipe: no builtin on gfx950.
__device__ __forceinline__ u32 cvtpk(float a, float b) {
  u32 r;
  asm("v_cvt_pk_bf16_f32 %0, %1, %2" : "=v"(r) : "v"(a), "v"(b));
  return r;
}
// Cross-lane row swaps (gfx950). Both operands are read-write.
__device__ __forceinline__ void p32swap(u32& a, u32& b) {
  asm("v_permlane32_swap_b32 %0, %1" : "+v"(a), "+v"(b));
}
__device__ __forceinline__ void p16swap(u32& a, u32& b) {
  asm("v_permlane16_swap_b32 %0, %1" : "+v"(a), "+v"(b));
}
__device__ __forceinline__ float ldf(const void* p, size_t i, int f32) {
  return f32 ? ((const float*)p)[i] : b2f(((const u16*)p)[i]);
}

// fp32 vs bf16 input detector (HW-verified; fp32 on this harness).
// Kept for the reduced-workspace fallback paths.
__global__ __launch_bounds__(256) void detect_dtype(const u16* __restrict__ x,
                                                    int* __restrict__ flag) {
  __shared__ int cnt;
  if (threadIdx.x == 0) cnt = 0;
  __syncthreads();
  int local = 0;
  for (int p = threadIdx.x; p < 512; p += 256) {
    int e = (x[2 * p] >> 7) & 0xFF;
    if (e >= 0xC0) local++;
  }
  atomicAdd(&cnt, local);
  __syncthreads();
  if (threadIdx.x == 0) flag[0] = (cnt >= 16) ? 1 : 0;
}

// Fused one-time fp32->bf16 convert of all 5 tensors (1 launch, self-detecting).
__global__ __launch_bounds__(256) void convert_all(
    const void* __restrict__ px, const void* __restrict__ pwq,
    const void* __restrict__ pbq, const void* __restrict__ pwo,
    const void* __restrict__ pbo, u16* __restrict__ xb,
    u16* __restrict__ wqkvb, u16* __restrict__ bqkvb, u16* __restrict__ wob,
    u16* __restrict__ bob) {
  __shared__ int sf;
  if (threadIdx.x == 0) sf = 0;
  __syncthreads();
  {
    const u16* xr = (const u16*)px;
    int local = 0;
    for (int p = threadIdx.x; p < 512; p += 256) {
      int e = (xr[2 * p] >> 7) & 0xFF;
      if (e >= 0xC0) local++;
    }
    atomicAdd(&sf, local);
  }
  __syncthreads();
  const int isf32 = (sf >= 16);

  int i = blockIdx.x * 256 + threadIdx.x;
  const void* in; u16* out; size_t g;
  if (i < 524288)       { in = px;  out = xb;    g = (size_t)i; }
  else if (i < 917504)  { in = pwq; out = wqkvb; g = (size_t)(i - 524288); }
  else if (i < 917888)  { in = pbq; out = bqkvb; g = (size_t)(i - 917504); }
  else if (i < 1048960) { in = pwo; out = wob;   g = (size_t)(i - 917888); }
  else                  { in = pbo; out = bob;   g = (size_t)(i - 1048960); }
  size_t base = g * 8;
  if (isf32) {
    const float* p = (const float*)in + base;
    float4 v0 = *(const float4*)p, v1 = *(const float4*)(p + 4);
    union { short8 v; u16 e[8]; } t;
    t.e[0]=f2b(v0.x); t.e[1]=f2b(v0.y); t.e[2]=f2b(v0.z); t.e[3]=f2b(v0.w);
    t.e[4]=f2b(v1.x); t.e[5]=f2b(v1.y); t.e[6]=f2b(v1.z); t.e[7]=f2b(v1.w);
    *(short8*)(out + base) = t.v;
  } else {
    *(short8*)(out + base) = *(const short8*)((const u16*)in + base);
  }
}

// qkv[n][3072] V-cols -> Vtg[h][64][4096]  (HW-verified)
__global__ __launch_bounds__(256) void transpose_v(const u16* __restrict__ qkv,
                                                   u16* __restrict__ Vt) {
  __shared__ u16 T[64 * 72];
  const int tid = threadIdx.x;
  const int h = blockIdx.y;
  const int s0 = blockIdx.x * 64;
  for (int r = 0; r < 2; ++r) {
    int cid = r * 256 + tid;
    int s = cid >> 3, c8 = cid & 7;
    union { short8 v; u16 u[8]; } uu;
    uu.v = *(const short8*)(qkv + (size_t)(s0 + s) * 3072 + 2048 + h * 64 + c8 * 8);
    for (int i = 0; i < 8; ++i) T[(c8 * 8 + i) * 72 + s] = uu.u[i];
  }
  __syncthreads();
  for (int r = 0; r < 2; ++r) {
    int cid = r * 256 + tid;
    int dd = cid >> 3, c8 = cid & 7;
    union { short8 v; u16 u[8]; } uu;
    for (int i = 0; i < 8; ++i) uu.u[i] = T[dd * 72 + c8 * 8 + i];
    *(short8*)(Vt + (size_t)(h * 64 + dd) * 4096 + s0 + c8 * 8) = uu.v;
  }
}

// gemm1 double-buffered (r10-verified: -15.5 µs vs single-buffered):
// bf16 A[M][K]*B[N][K]^T + bias -> bf16 C. Prefetch one K-tile ahead into
// the other LDS buffer, ONE barrier/iter.
__global__ __launch_bounds__(256) void gemm1_db(const u16* __restrict__ A,
                                                const u16* __restrict__ B,
                                                const u16* __restrict__ bias,
                                                u16* __restrict__ C,
                                                int K, int lda, int ldb, int ldc) {
  __shared__ __align__(16) u16 sm[2][16384];  // per buf: A(8192 u16)|B(8192 u16)
  const int tid = threadIdx.x;
  const int w = tid >> 6, lane = tid & 63;
  const int lq = lane & 15, qr = lane >> 4;
  const int m0 = blockIdx.y * 128, n0 = blockIdx.x * 128;
  const int wm = (w >> 1) * 64, wn = (w & 1) * 64;

  f32x4 acc[4][4];
  for (int i = 0; i < 4; i++)
    for (int j = 0; j < 4; j++) acc[i][j] = (f32x4){0.f, 0.f, 0.f, 0.f};
  float bv[4];
  for (int ns = 0; ns < 4; ++ns) bv[ns] = b2f(bias[n0 + wn + ns * 16 + lq]);

  const int rs = tid >> 3, cs = tid & 7;
  const u16* gA = A + (size_t)(m0 + rs) * lda + cs * 8;
  const u16* gB = B + (size_t)(n0 + rs) * ldb + cs * 8;
  const int lofs = (tid & ~63) << 3;  // wave-uniform; HW adds lane*16B

#define GSTAGE(buf, k0)                                                      \
  do {                                                                       \
    u16* As_ = &sm[buf][0];                                                  \
    u16* Bs_ = &sm[buf][8192];                                               \
    for (int r = 0; r < 4; ++r) {                                            \
      __builtin_amdgcn_global_load_lds(gA + (size_t)(r * 32) * lda + (k0),   \
                                       As_ + lofs + r * 2048, 16, 0, 0);     \
      __builtin_amdgcn_global_load_lds(gB + (size_t)(r * 32) * ldb + (k0),   \
                                       Bs_ + lofs + r * 2048, 16, 0, 0);     \
    }                                                                        \
  } while (0)

  GSTAGE(0, 0);
  __syncthreads();  // drain prologue loads

  const int nk = K >> 6;
  for (int kt = 0; kt < nk; ++kt) {
    const int cur = kt & 1;
    if (kt + 1 < nk) GSTAGE(cur ^ 1, (kt + 1) * 64);  // prefetch next tile
    const u16* As = &sm[cur][0];
    const u16* Bs = &sm[cur][8192];
    for (int ks = 0; ks < 2; ++ks) {
      short8 af[4], bf[4];
      const int sw = ks * 4 + qr;
      for (int i = 0; i < 4; i++) {
        af[i] = *(const short8*)(As + (wm + i * 16 + lq) * 64 + sw * 8);
        bf[i] = *(const short8*)(Bs + (wn + i * 16 + lq) * 64 + sw * 8);
      }
      for (int mi = 0; mi < 4; mi++)
        for (int ni = 0; ni < 4; ni++)
          acc[mi][ni] = __builtin_amdgcn_mfma_f32_16x16x32_bf16(
              af[mi], bf[ni], acc[mi][ni], 0, 0, 0);
    }
    __syncthreads();  // reads-done for buf[cur] + drains next-tile loads
  }
#undef GSTAGE

  // bf16 epilogue (verified layout, stride 132) into the flat 64KB LDS
  u16* SH = &sm[0][0];
  for (int mi = 0; mi < 4; mi++)
    for (int ni = 0; ni < 4; ni++)
      for (int r = 0; r < 4; ++r)
        SH[(wm + mi * 16 + qr * 4 + r) * 132 + wn + ni * 16 + lq] =
            f2b(acc[mi][ni][r] + bv[ni]);
  __syncthreads();
  for (int it = 0; it < 8; ++it) {
    int idx = it * 256 + tid;
    int row = idx >> 4, c8 = idx & 15;
    *(short8*)(C + (size_t)(m0 + row) * ldc + n0 + c8 * 8) =
        *(const short8*)(SH + row * 132 + c8 * 8);
  }
}

// gemm2 double-buffered (r11): same staging/loop as gemm1_db (r10-verified),
// fp32 direct-store epilogue (r8-verified). Replaces gemm_bt_ks (r9: K-split
// was null — lockstep waves don't overlap; dbuf prefetch is the proven fix,
// and gemm2's 1 block/CU occupancy makes exposed latency worst-case here).
__global__ __launch_bounds__(256) void gemm2_db(const u16* __restrict__ A,
                                                const u16* __restrict__ B,
                                                const u16* __restrict__ bias,
                                                float* __restrict__ C,
                                                int K, int lda, int ldb, int ldc) {
  __shared__ __align__(16) u16 sm[2][16384];
  const int tid = threadIdx.x;
  const int w = tid >> 6, lane = tid & 63;
  const int lq = lane & 15, qr = lane >> 4;
  const int m0 = blockIdx.y * 128, n0 = blockIdx.x * 128;
  const int wm = (w >> 1) * 64, wn = (w & 1) * 64;

  f32x4 acc[4][4];
  for (int i = 0; i < 4; i++)
    for (int j = 0; j < 4; j++) acc[i][j] = (f32x4){0.f, 0.f, 0.f, 0.f};
  float bv[4];
  for (int ns = 0; ns < 4; ++ns) bv[ns] = b2f(bias[n0 + wn + ns * 16 + lq]);

  const int rs = tid >> 3, cs = tid & 7;
  const u16* gA = A + (size_t)(m0 + rs) * lda + cs * 8;
  const u16* gB = B + (size_t)(n0 + rs) * ldb + cs * 8;
  const int lofs = (tid & ~63) << 3;

#define GSTAGE(buf, k0)                                                      \
  do {                                                                       \
    u16* As_ = &sm[buf][0];                                                  \
    u16* Bs_ = &sm[buf][8192];                                               \
    for (int r = 0; r < 4; ++r) {                                            \
      __builtin_amdgcn_global_load_lds(gA + (size_t)(r * 32) * lda + (k0),   \
                                       As_ + lofs + r * 2048, 16, 0, 0);     \
      __builtin_amdgcn_global_load_lds(gB + (size_t)(r * 32) * ldb + (k0),   \
                                       Bs_ + lofs + r * 2048, 16, 0, 0);     \
    }                                                                        \
  } while (0)

  GSTAGE(0, 0);
  __syncthreads();

  const int nk = K >> 6;
  for (int kt = 0; kt < nk; ++kt) {
    const int cur = kt & 1;
    if (kt + 1 < nk) GSTAGE(cur ^ 1, (kt + 1) * 64);
    const u16* As = &sm[cur][0];
    const u16* Bs = &sm[cur][8192];
    for (int ks = 0; ks < 2; ++ks) {
      short8 af[4], bf[4];
      const int sw = ks * 4 + qr;
      for (int i = 0; i < 4; i++) {
        af[i] = *(const short8*)(As + (wm + i * 16 + lq) * 64 + sw * 8);
        bf[i] = *(const short8*)(Bs + (wn + i * 16 + lq) * 64 + sw * 8);
      }
      for (int mi = 0; mi < 4; mi++)
        for (int ni = 0; ni < 4; ni++)
          acc[mi][ni] = __builtin_amdgcn_mfma_f32_16x16x32_bf16(
              af[mi], bf[ni], acc[mi][ni], 0, 0, 0);
    }
    __syncthreads();
  }
#undef GSTAGE

  // direct fp32 stores (r8-verified): no LDS roundtrip, no barriers
  for (int mi = 0; mi < 4; mi++) {
    int row = m0 + wm + mi * 16 + qr * 4;
    for (int r = 0; r < 4; ++r) {
      float* rp = C + (size_t)(row + r) * ldc + n0 + wn;
      for (int ni = 0; ni < 4; ni++)
        rp[ni * 16 + lq] = acc[mi][ni][r] + bv[ni];
    }
  }
}

// C[M][N] = A[M][K]*B[N][K]^T + bias[N]; r2-verified core; r8 direct fp32
// epilogue. Used for the fallback paths.
__global__ __launch_bounds__(256) void gemm_bt(const void* __restrict__ A,
                                               const void* __restrict__ B,
                                               const void* __restrict__ bias,
                                               void* __restrict__ C,
                                               int M, int N, int K,
                                               int lda, int ldb, int ldc,
                                               int aMay, int bMay, int outF32,
                                               const int* __restrict__ flag) {
  __shared__ __align__(16) u16 sm[128 * 132];  // 33792 B; reused by epilogue
  u16* As = sm;
  u16* Bs = sm + 128 * 64;
  const int f = flag[0];
  const int a32 = aMay && f, b32 = bMay && f;
  const int tid = threadIdx.x;
  const int w = tid >> 6, lane = tid & 63;
  const int lq = lane & 15, qr = lane >> 4;
  const int m0 = blockIdx.y * 128, n0 = blockIdx.x * 128;
  const int wm = (w >> 1) * 64, wn = (w & 1) * 64;

  f32x4 acc[4][4];
  for (int i = 0; i < 4; i++)
    for (int j = 0; j < 4; j++) acc[i][j] = (f32x4){0.f, 0.f, 0.f, 0.f};
  float bv[4];
  for (int ns = 0; ns < 4; ++ns) bv[ns] = ldf(bias, n0 + wn + ns * 16 + lq, b32);

  // hoisted staging addresses (bf16 fast path)
  const int rs = tid >> 3, cs = tid & 7;
  const u16* gA = (const u16*)A + (size_t)(m0 + rs) * lda + cs * 8;
  const u16* gB = (const u16*)B + (size_t)(n0 + rs) * ldb + cs * 8;
  u16* lA = As + ((tid & ~63) << 3);  // wave-uniform base; HW adds lane*16B
  u16* lB = Bs + ((tid & ~63) << 3);

  for (int k0 = 0; k0 < K; k0 += 64) {
    if (!(a32 | b32)) {
      for (int r = 0; r < 4; ++r) {
        __builtin_amdgcn_global_load_lds(gA + (size_t)(r * 32) * lda + k0,
                                         lA + r * 2048, 16, 0, 0);
        __builtin_amdgcn_global_load_lds(gB + (size_t)(r * 32) * ldb + k0,
                                         lB + r * 2048, 16, 0, 0);
      }
    } else {
      for (int r = 0; r < 4; ++r) {
        int cid = r * 256 + tid;
        int row = cid >> 3, c = cid & 7;
        if (a32) {
          const float* p = (const float*)A + (size_t)(m0 + row) * lda + k0 + c * 8;
          float4 v0 = *(const float4*)p, v1 = *(const float4*)(p + 4);
          union { short8 v; u16 e[8]; } t;
          t.e[0]=f2b(v0.x); t.e[1]=f2b(v0.y); t.e[2]=f2b(v0.z); t.e[3]=f2b(v0.w);
          t.e[4]=f2b(v1.x); t.e[5]=f2b(v1.y); t.e[6]=f2b(v1.z); t.e[7]=f2b(v1.w);
          *(short8*)(As + row * 64 + c * 8) = t.v;
        } else {
          *(short8*)(As + row * 64 + c * 8) =
              *(const short8*)((const u16*)A + (size_t)(m0 + row) * lda + k0 + c * 8);
        }
        if (b32) {
          const float* p = (const float*)B + (size_t)(n0 + row) * ldb + k0 + c * 8;
          float4 v0 = *(const float4*)p, v1 = *(const float4*)(p + 4);
          union { short8 v; u16 e[8]; } t;
          t.e[0]=f2b(v0.x); t.e[1]=f2b(v0.y); t.e[2]=f2b(v0.z); t.e[3]=f2b(v0.w);
          t.e[4]=f2b(v1.x); t.e[5]=f2b(v1.y); t.e[6]=f2b(v1.z); t.e[7]=f2b(v1.w);
          *(short8*)(Bs + row * 64 + c * 8) = t.v;
        } else {
          *(short8*)(Bs + row * 64 + c * 8) =
              *(const short8*)((const u16*)B + (size_t)(n0 + row) * ldb + k0 + c * 8);
        }
      }
    }
    __syncthreads();
    for (int ks = 0; ks < 2; ++ks) {
      short8 af[4], bf[4];
      const int sw = ks * 4 + qr;
      for (int i = 0; i < 4; i++) {
        af[i] = *(const short8*)(As + (wm + i * 16 + lq) * 64 + sw * 8);
        bf[i] = *(const short8*)(Bs + (wn + i * 16 + lq) * 64 + sw * 8);
      }
      for (int mi = 0; mi < 4; mi++)
        for (int ni = 0; ni < 4; ni++)
          acc[mi][ni] = __builtin_amdgcn_mfma_f32_16x16x32_bf16(
              af[mi], bf[ni], acc[mi][ni], 0, 0, 0);
    }
    __syncthreads();
  }

  if (!outF32) {
    u16* SH = sm;
    for (int mi = 0; mi < 4; mi++)
      for (int ni = 0; ni < 4; ni++)
        for (int r = 0; r < 4; ++r)
          SH[(wm + mi * 16 + qr * 4 + r) * 132 + wn + ni * 16 + lq] =
              f2b(acc[mi][ni][r] + bv[ni]);
    __syncthreads();
    for (int it = 0; it < 8; ++it) {
      int idx = it * 256 + tid;
      int row = idx >> 4, c8 = idx & 15;
      *(short8*)((u16*)C + (size_t)(m0 + row) * ldc + n0 + c8 * 8) =
          *(const short8*)(SH + row * 132 + c8 * 8);
    }
  } else {
    // direct fp32 stores (r8): no LDS roundtrip, no barriers
    float* Cf = (float*)C;
    for (int mi = 0; mi < 4; mi++) {
      int row = m0 + wm + mi * 16 + qr * 4;
      for (int r = 0; r < 4; ++r) {
        float* rp = Cf + (size_t)(row + r) * ldc + n0 + wn;
        for (int ni = 0; ni < 4; ni++)
          rp[ni * 16 + lq] = acc[mi][ni][r] + bv[ni];
      }
    }
  }
}

// Flash attention (r7-verified, ~90 µs): KV-split + glds staging + dbuf +
// one barrier/iter; r7 combine epilogue (two stride-17 rounds).
__global__ __launch_bounds__(512, 2) void attn_split(const u16* __restrict__ qkv,
                                                     const u16* __restrict__ Vtg,
                                                     u16* __restrict__ ctx, int ldctx) {
  __shared__ __align__(16) u16 SMEM[2][16384];
  const int tid = threadIdx.x;
  const int w = tid >> 6, lane = tid & 63;
  const int half = w >> 2, wq = w & 3, wl = w & 3;
  const int lq = lane & 15, qr = lane >> 4;
  const int qb = blockIdx.x, h = blockIdx.y;
  const int qbase = qb * 128 + wq * 32;
  const float cs = 0.18033688011112042f;  // log2(e)/8

  short8 qf[2][2];
#pragma unroll
  for (int mi = 0; mi < 2; ++mi)
#pragma unroll
    for (int ks = 0; ks < 2; ++ks)
      qf[mi][ks] = *(const short8*)(qkv + (size_t)(qbase + mi * 16 + lq) * 3072 +
                                    h * 64 + ks * 32 + qr * 8);

  f32x4 o[2][4];
#pragma unroll
  for (int mi = 0; mi < 2; ++mi)
#pragma unroll
    for (int ds = 0; ds < 4; ++ds) o[mi][ds] = (f32x4){0.f, 0.f, 0.f, 0.f};
  float lrow[2] = {0.f, 0.f};

  // staging: per-lane pre-swizzled global sources; wave-uniform LDS bases.
  const int csw = ((lane & 7) ^ (lane >> 3)) << 3;
  const int r0v = wl * 8 + (lane >> 3);  // row covered by this lane
  const u16* sK0 = qkv + (size_t)(half * 2048 + r0v) * 3072 + 1024 + h * 64 + csw;
  const u16* sK1 = sK0 + (size_t)32 * 3072;
  const u16* sV0 = Vtg + (size_t)(h * 64 + r0v) * 4096 + half * 2048 + csw;
  const u16* sV1 = sV0 + (size_t)32 * 4096;
  const int kb = half * 4096 + wl * 512;         // u16 offset, wave-uniform
  const int vb = 8192 + half * 4096 + wl * 512;

#define STAGE(buf)                                                          \
  do {                                                                      \
    u16* B_ = &SMEM[buf][0];                                                \
    __builtin_amdgcn_global_load_lds(sK0, B_ + kb, 16, 0, 0);               \
    __builtin_amdgcn_global_load_lds(sK1, B_ + kb + 2048, 16, 0, 0);        \
    __builtin_amdgcn_global_load_lds(sV0, B_ + vb, 16, 0, 0);               \
    __builtin_amdgcn_global_load_lds(sV1, B_ + vb + 2048, 16, 0, 0);        \
    sK0 += (size_t)64 * 3072; sK1 += (size_t)64 * 3072;                     \
    sV0 += 64; sV1 += 64;                                                   \
  } while (0)

  STAGE(0);
  __syncthreads();  // drain prologue loads + sync

  for (int it = 0; it < 32; ++it) {
    const int cur = it & 1;
    if (it + 1 < 32) STAGE(cur ^ 1);  // next tile; drains at loop-end barrier
    const u16* Kh = &SMEM[cur][half * 4096];
    const u16* Vh = &SMEM[cur][8192 + half * 4096];

    // QK^T (swapped: K is A-operand, Q is B-operand)
    f32x4 s[2][4];
#pragma unroll
    for (int mi = 0; mi < 2; ++mi)
#pragma unroll
      for (int ns = 0; ns < 4; ++ns) s[mi][ns] = (f32x4){0.f, 0.f, 0.f, 0.f};
#pragma unroll
    for (int ks = 0; ks < 2; ++ks) {
      short8 kf[4];
#pragma unroll
      for (int ns = 0; ns < 4; ++ns) {
        int rk = ns * 16 + lq;
        kf[ns] = *(const short8*)(Kh + rk * 64 + (((ks * 4 + qr) ^ (lq & 7)) << 3));
      }
      __builtin_amdgcn_s_setprio(1);
#pragma unroll
      for (int mi = 0; mi < 2; ++mi)
#pragma unroll
        for (int ns = 0; ns < 4; ++ns)
          s[mi][ns] = __builtin_amdgcn_mfma_f32_16x16x32_bf16(
              kf[ns], qf[mi][ks], s[mi][ns], 0, 0, 0);
      __builtin_amdgcn_s_setprio(0);
    }

    // fixed-max softmax + in-register P exchange (T12)
    short8 pf[2][2];
#pragma unroll
    for (int mi = 0; mi < 2; ++mi) {
      float lacc = 0.f;
      u32 X[4], Y[4];
#pragma unroll
      for (int ns = 0; ns < 4; ++ns) {
        float p0 = __builtin_amdgcn_exp2f(fmaf(s[mi][ns][0], cs, -12.0f));
        float p1 = __builtin_amdgcn_exp2f(fmaf(s[mi][ns][1], cs, -12.0f));
        float p2 = __builtin_amdgcn_exp2f(fmaf(s[mi][ns][2], cs, -12.0f));
        float p3 = __builtin_amdgcn_exp2f(fmaf(s[mi][ns][3], cs, -12.0f));
        lacc += (p0 + p1) + (p2 + p3);
        X[ns] = cvtpk(p0, p1);
        Y[ns] = cvtpk(p2, p3);
      }
      lrow[mi] += lacc;
#pragma unroll
      for (int ks = 0; ks < 2; ++ks) {
        u32 a0 = X[2 * ks], b0 = X[2 * ks + 1];
        u32 a1 = Y[2 * ks], b1 = Y[2 * ks + 1];
        p32swap(a0, b0); p16swap(a0, b0);
        p32swap(a1, b1); p16swap(a1, b1);
        union { u32 u[4]; short8 v; } t;
        t.u[0] = a0; t.u[1] = a1; t.u[2] = b0; t.u[3] = b1;
        pf[mi][ks] = t.v;
      }
    }

    // PV (swapped: V is A-operand, P is B-operand)
#pragma unroll
    for (int ks = 0; ks < 2; ++ks) {
      short8 vf[4];
#pragma unroll
      for (int ds = 0; ds < 4; ++ds) {
        int dv = ds * 16 + lq;
        vf[ds] = *(const short8*)(Vh + (size_t)dv * 64 +
                                  (((ks * 4 + qr) ^ (lq & 7)) << 3));
      }
      __builtin_amdgcn_s_setprio(1);
#pragma unroll
      for (int mi = 0; mi < 2; ++mi)
#pragma unroll
        for (int ds = 0; ds < 4; ++ds)
          o[mi][ds] = __builtin_amdgcn_mfma_f32_16x16x32_bf16(
              vf[ds], pf[mi][ks], o[mi][ds], 0, 0, 0);
      __builtin_amdgcn_s_setprio(0);
    }
    __syncthreads();  // compute-done + vmcnt(0) drain of next-tile loads
  }
#undef STAGE

  // in-block combine (r7-verified): per-mi rounds, stride-17 fp32 regions.
  float* CB = (float*)&SMEM[0][0];
#pragma unroll
  for (int mi = 0; mi < 2; ++mi) {
    float* p = CB + (size_t)(wq * 64 + lane) * 17;
    if (half == 1) {
#pragma unroll
      for (int ds = 0; ds < 4; ++ds) {
        p[ds * 4 + 0] = o[mi][ds][0];
        p[ds * 4 + 1] = o[mi][ds][1];
        p[ds * 4 + 2] = o[mi][ds][2];
        p[ds * 4 + 3] = o[mi][ds][3];
      }
      p[16] = lrow[mi];
    }
    __syncthreads();
    if (half == 0) {
#pragma unroll
      for (int ds = 0; ds < 4; ++ds) {
        o[mi][ds][0] += p[ds * 4 + 0];
        o[mi][ds][1] += p[ds * 4 + 1];
        o[mi][ds][2] += p[ds * 4 + 2];
        o[mi][ds][3] += p[ds * 4 + 3];
      }
      lrow[mi] += p[16];
    }
    __syncthreads();
  }

  if (half == 0) {
#pragma unroll
    for (int mi = 0; mi < 2; ++mi) {
      float l = lrow[mi];
      l += __shfl_xor(l, 16, 64);
      l += __shfl_xor(l, 32, 64);
      float linv = 1.f / fmaxf(l, 1e-30f);
      int row = qbase + mi * 16 + lq;
      u16* dst = ctx + (size_t)row * ldctx + h * 64 + qr * 4;
#pragma unroll
      for (int ds = 0; ds < 4; ++ds) {
        u32 lo = cvtpk(o[mi][ds][0] * linv, o[mi][ds][1] * linv);
        u32 hi = cvtpk(o[mi][ds][2] * linv, o[mi][ds][3] * linv);
        *(uint2*)(dst + ds * 16) = make_uint2(lo, hi);
      }
    }
  }
}

// Legacy v7 kernel (256 threads) kept ONLY for the no-workspace fallback.
__global__ __launch_bounds__(256) void attn_fused(const u16* __restrict__ qkv,
                                                  const u16* __restrict__ Vtg,
                                                  u16* __restrict__ ctx, int ldctx) {
  __shared__ u16 Ks[64 * 64];
  __shared__ u16 Vts[64 * 64];
  const int tid = threadIdx.x;
  const int w = tid >> 6, lane = tid & 63;
  const int lq = lane & 15, qr = lane >> 4;
  const int qb = blockIdx.x, h = blockIdx.y;
  const int qbase = qb * 128 + w * 32;
  const float cs = 0.18033688011112042f;

  short8 qf[2][2];
  for (int mi = 0; mi < 2; ++mi)
    for (int ks = 0; ks < 2; ++ks)
      qf[mi][ks] = *(const short8*)(qkv + (size_t)(qbase + mi * 16 + lq) * 3072 +
                                    h * 64 + ks * 32 + qr * 8);

  f32x4 o[2][4];
  for (int mi = 0; mi < 2; ++mi)
    for (int ds = 0; ds < 4; ++ds) o[mi][ds] = (f32x4){0.f, 0.f, 0.f, 0.f};
  float lrow[2] = {0.f, 0.f};

  const int c = tid & 7, r0 = tid >> 3;
  u16* dKA = Ks + r0 * 64 + ((c ^ (r0 & 7)) << 3);
  u16* dKB = dKA + 32 * 64;
  const u16* sKA = qkv + (size_t)r0 * 3072 + 1024 + h * 64 + c * 8;
  const u16* sKB = sKA + (size_t)32 * 3072;
  const u16* sVfA = qkv + (size_t)r0 * 3072 + 2048 + h * 64 + c * 8;
  const u16* sVfB = sVfA + (size_t)32 * 3072;

  short8 rKA, rKB;
  union { short8 v; u16 e[8]; } ufA, ufB;
  rKA = *(const short8*)sKA; sKA += (size_t)64 * 3072;
  rKB = *(const short8*)sKB; sKB += (size_t)64 * 3072;
  ufA.v = *(const short8*)sVfA; sVfA += (size_t)64 * 3072;
  ufB.v = *(const short8*)sVfB; sVfB += (size_t)64 * 3072;

  for (int j0 = 0; j0 < 4096; j0 += 64) {
    __syncthreads();
    *(short8*)dKA = rKA;
    *(short8*)dKB = rKB;
    {
      const int jc = r0 >> 3;
      for (int i = 0; i < 8; ++i)
        Vts[(c * 8 + i) * 64 + ((jc ^ i) << 3) + (r0 & 7)] = ufA.e[i];
    }
    {
      const int jc = (r0 + 32) >> 3;
      for (int i = 0; i < 8; ++i)
        Vts[(c * 8 + i) * 64 + ((jc ^ i) << 3) + (r0 & 7)] = ufB.e[i];
    }
    __syncthreads();

    if (j0 + 64 < 4096) {
      rKA = *(const short8*)sKA; sKA += (size_t)64 * 3072;
      rKB = *(const short8*)sKB; sKB += (size_t)64 * 3072;
      ufA.v = *(const short8*)sVfA; sVfA += (size_t)64 * 3072;
      ufB.v = *(const short8*)sVfB; sVfB += (size_t)64 * 3072;
    }

    f32x4 s[2][4];
    for (int mi = 0; mi < 2; ++mi)
      for (int ns = 0; ns < 4; ++ns) s[mi][ns] = (f32x4){0.f, 0.f, 0.f, 0.f};
    for (int ks = 0; ks < 2; ++ks) {
      short8 kf[4];
      for (int ns = 0; ns < 4; ++ns) {
        int rk = ns * 16 + lq;
        kf[ns] = *(const short8*)(Ks + rk * 64 + (((ks * 4 + qr) ^ (lq & 7)) << 3));
      }
      __builtin_amdgcn_s_setprio(1);
      for (int mi = 0; mi < 2; ++mi)
        for (int ns = 0; ns < 4; ++ns)
          s[mi][ns] = __builtin_amdgcn_mfma_f32_16x16x32_bf16(
              kf[ns], qf[mi][ks], s[mi][ns], 0, 0, 0);
      __builtin_amdgcn_s_setprio(0);
    }

    short8 pf[2][2];
#pragma unroll
    for (int mi = 0; mi < 2; ++mi) {
      float lacc = 0.f;
      u32 X[4], Y[4];
#pragma unroll
      for (int ns = 0; ns < 4; ++ns) {
        float p0 = __builtin_amdgcn_exp2f(fmaf(s[mi][ns][0], cs, -12.0f));
        float p1 = __builtin_amdgcn_exp2f(fmaf(s[mi][ns][1], cs, -12.0f));
        float p2 = __builtin_amdgcn_exp2f(fmaf(s[mi][ns][2], cs, -12.0f));
        float p3 = __builtin_amdgcn_exp2f(fmaf(s[mi][ns][3], cs, -12.0f));
        lacc += (p0 + p1) + (p2 + p3);
        X[ns] = cvtpk(p0, p1);
        Y[ns] = cvtpk(p2, p3);
      }
      lrow[mi] += lacc;
#pragma unroll
      for (int ks = 0; ks < 2; ++ks) {
        u32 a0 = X[2 * ks], b0 = X[2 * ks + 1];
        u32 a1 = Y[2 * ks], b1 = Y[2 * ks + 1];
        p32swap(a0, b0); p16swap(a0, b0);
        p32swap(a1, b1); p16swap(a1, b1);
        union { u32 u[4]; short8 v; } t;
        t.u[0] = a0; t.u[1] = a1; t.u[2] = b0; t.u[3] = b1;
        pf[mi][ks] = t.v;
      }
    }

    for (int ks = 0; ks < 2; ++ks) {
      short8 vf[4];
      for (int ds = 0; ds < 4; ++ds) {
        int dv = ds * 16 + lq;
        vf[ds] = *(const short8*)(Vts + (size_t)dv * 64 +
                                  (((ks * 4 + qr) ^ (lq & 7)) << 3));
      }
      __builtin_amdgcn_s_setprio(1);
      for (int mi = 0; mi < 2; ++mi)
        for (int ds = 0; ds < 4; ++ds)
          o[mi][ds] = __builtin_amdgcn_mfma_f32_16x16x32_bf16(
              vf[ds], pf[mi][ks], o[mi][ds], 0, 0, 0);
      __builtin_amdgcn_s_setprio(0);
    }
  }

  for (int mi = 0; mi < 2; ++mi) {
    float l = lrow[mi];
    l += __shfl_xor(l, 16, 64);
    l += __shfl_xor(l, 32, 64);
    float linv = 1.f / fmaxf(l, 1e-30f);
    int row = qbase + mi * 16 + lq;
    u16* dst = ctx + (size_t)row * ldctx + h * 64 + qr * 4;
    for (int ds = 0; ds < 4; ++ds) {
      u32 lo = cvtpk(o[mi][ds][0] * linv, o[mi][ds][1] * linv);
      u32 hi = cvtpk(o[mi][ds][2] * linv, o[mi][ds][3] * linv);
      *(uint2*)(dst + ds * 16) = make_uint2(lo, hi);
    }
  }
}

extern "C" void kernel_launch(void* const* d_in, const int* in_sizes, int n_in,
                              void* d_out, int out_size, void* d_ws, size_t ws_size,
                              hipStream_t stream) {
  float* out = (float*)d_out;  // reference output dtype is fp32

  const void *px = nullptr, *pwq = nullptr, *pbq = nullptr, *pwo = nullptr, *pbo = nullptr;
  if (n_in == 5) {
    for (int i = 0; i < 5; ++i) {
      switch (in_sizes[i]) {
        case 4194304: px = d_in[i]; break;
        case 3145728: pwq = d_in[i]; break;
        case 3072:    pbq = d_in[i]; break;
        case 1048576: pwo = d_in[i]; break;
        case 1024:    pbo = d_in[i]; break;
        default: break;
      }
    }
  }
  if (!px || !pwq || !pbq || !pwo || !pbo) {
    px = d_in[0]; pwq = d_in[1]; pbq = d_in[2]; pwo = d_in[3]; pbo = d_in[4];
  }

  int* flag = (int*)d_ws;
  u16* qkv = (u16*)((char*)d_ws + 64);
  u16* ctx = qkv;  // aliases dead Q-region (row stride 3072); race-free per block

  const size_t nQKV = (size_t)4096 * 3072;
  const size_t nVt = (size_t)16 * 64 * 4096;
  const size_t nx = 4194304, nwq = 3145728, nwo = 1048576;
  u16* Vtg = qkv + nQKV;
  const size_t need_vt = 64 + (nQKV + nVt) * 2;
  const size_t need_full = need_vt + (nx + nwq + 4096 + nwo + 1024) * 2;

  if (ws_size >= need_full) {
    u16* xb    = Vtg + nVt;
    u16* wqkvb = xb + nx;
    u16* bqkvb = wqkvb + nwq;
    u16* wob   = bqkvb + 4096;
    u16* bob   = wob + nwo;
    convert_all<<<4098, 256, 0, stream>>>(px, pwq, pbq, pwo, pbo,
                                          xb, wqkvb, bqkvb, wob, bob);

    gemm1_db<<<dim3(24, 32), 256, 0, stream>>>(xb, wqkvb, bqkvb, qkv,
                                               1024, 1024, 1024, 3072);
    transpose_v<<<dim3(64, 16), 256, 0, stream>>>(qkv, Vtg);
    attn_split<<<dim3(32, 16), 512, 0, stream>>>(qkv, Vtg, ctx, 3072);
    gemm2_db<<<dim3(8, 32), 256, 0, stream>>>(ctx, wob, bob, out,
                                              1024, 3072, 1024, 1024);
  } else if (ws_size >= need_vt) {
    detect_dtype<<<1, 256, 0, stream>>>((const u16*)px, flag);
    gemm_bt<<<dim3(24, 32), 256, 0, stream>>>(px, pwq, pbq, qkv,
                                              4096, 3072, 1024, 1024, 1024, 3072,
                                              1, 1, 0, flag);
    transpose_v<<<dim3(64, 16), 256, 0, stream>>>(qkv, Vtg);
    attn_split<<<dim3(32, 16), 512, 0, stream>>>(qkv, Vtg, ctx, 3072);
    gemm_bt<<<dim3(8, 32), 256, 0, stream>>>(ctx, pwo, pbo, out,
                                             4096, 1024, 1024, 3072, 1024, 1024,
                                             0, 1, 1, flag);
  } else {
    detect_dtype<<<1, 256, 0, stream>>>((const u16*)px, flag);
    gemm_bt<<<dim3(24, 32), 256, 0, stream>>>(px, pwq, pbq, qkv,
                                              4096, 3072, 1024, 1024, 1024, 3072,
                                              1, 1, 0, flag);
    attn_fused<<<dim3(32, 16), 256, 0, stream>>>(qkv, (const u16*)nullptr, ctx, 3072);
    gemm_bt<<<dim3(8, 32), 256, 0, stream>>>(ctx, pwo, pbo, out,
                                             4096, 1024, 1024, 3072, 1024, 1024,
                                             0, 1, 1, flag);
  }
}